// Round 11
// baseline (595.855 us; speedup 1.0000x reference)
//
#include <hip/hip_runtime.h>
#include <hip/hip_bf16.h>

// MSA Transformer block: B=1, S=64, L=256, DM=256, DP=128, H=8, HT=4, NO=32
// Round 11: OPM proj phase = LDS-staged GEMM (W through LDS, latency paid once
// per line not per use); pair residual prefetched at block start.

#define S_ 64
#define L_ 256
#define DM_ 256
#define DP_ 128
#define H_ 8
#define HT_ 4
#define NO_ 32

typedef __hip_bfloat16 bf16;
typedef short short4s __attribute__((ext_vector_type(4)));
typedef short short8 __attribute__((ext_vector_type(8)));
typedef float floatx4 __attribute__((ext_vector_type(4)));

__device__ __forceinline__ short f2bfs(float x) {
  union { float f; unsigned u; } v;
  v.f = x;
  unsigned r = (v.u + 0x7fffu + ((v.u >> 16) & 1u)) >> 16;
  return (short)r;
}

// ---------------- layernorm (4 rows per 256-thr block, 1 wave per row) ----------------
__global__ void k_ln(const float* __restrict__ src, bf16* __restrict__ dst,
                     const float* __restrict__ g, const float* __restrict__ bta, int D) {
  int row = blockIdx.x * 4 + (threadIdx.x >> 6);
  const float* x = src + (size_t)row * D;
  bf16* y = dst + (size_t)row * D;
  int t = threadIdx.x & 63;
  float v[4];
  int cnt = 0;
  float sum = 0.f;
  for (int e = t; e < D; e += 64) { float xv = x[e]; v[cnt++] = xv; sum += xv; }
  #pragma unroll
  for (int o = 32; o; o >>= 1) sum += __shfl_down(sum, o);
  sum = __shfl(sum, 0);
  float mean = sum / D;
  float var = 0.f;
  for (int k = 0; k < cnt; k++) { float d = v[k] - mean; var += d * d; }
  #pragma unroll
  for (int o = 32; o; o >>= 1) var += __shfl_down(var, o);
  var = __shfl(var, 0);
  float rstd = rsqrtf(var / D + 1e-5f);
  cnt = 0;
  for (int e = t; e < D; e += 64)
    y[e] = __float2bfloat16((v[cnt++] - mean) * rstd * g[e] + bta[e]);
}

// ---------------- weight transpose+convert: W[K,N] f32 -> Wt[N,K] bf16 ----------------
__global__ void k_wt(const float* __restrict__ W, bf16* __restrict__ Wt, int K, int N) {
  __shared__ float tile[32][33];
  int k0 = blockIdx.x * 32, n0 = blockIdx.y * 32;
  int tid = threadIdx.x; // 256
  for (int e = tid; e < 1024; e += 256) {
    int r = e >> 5, c = e & 31;
    tile[r][c] = W[(size_t)(k0 + r) * N + (n0 + c)];
  }
  __syncthreads();
  for (int e = tid; e < 1024; e += 256) {
    int r = e >> 5, c = e & 31;
    Wt[(size_t)(n0 + r) * K + (k0 + c)] = __float2bfloat16(tile[c][r]);
  }
}

// ---------------- OPM proj weight: W[(c*32+e)*128+d] -> Wt[d*1024 + e*32 + c] ----------------
__global__ void k_wtopm(const float* __restrict__ W, bf16* __restrict__ Wt) {
  int idx = blockIdx.x * 256 + threadIdx.x; // 131072
  int d = idx >> 10, kk = idx & 1023;
  int e = kk >> 5, c = kk & 31;
  Wt[idx] = __float2bfloat16(W[(size_t)(c * 32 + e) * 128 + d]);
}

// ---------------- OPM transpose: a_buf[(s*L+i)*32+c] -> a_t[(i*32+c)*64+s] ----------------
__global__ void k_topm(const bf16* __restrict__ in, bf16* __restrict__ out) {
  __shared__ bf16 tile[64][34];
  int i = blockIdx.x; // L_
  int tid = threadIdx.x; // 256
  for (int e = tid; e < 64 * 32; e += 256) {
    int s = e >> 5, c = e & 31;
    tile[s][c] = in[(size_t)s * (L_ * NO_) + i * NO_ + c];
  }
  __syncthreads();
  for (int e = tid; e < 64 * 32; e += 256) {
    int c = e >> 6, s = e & 63;
    out[((size_t)i * NO_ + c) * S_ + s] = tile[s][c];
  }
}

// ---------------- bf16 MFMA GEMM ----------------
// MODE: 0 Cf=v | 1 Cf+=v | 2 Cb=bf16(v) | 3 Cb=bf16(relu v) | 4 Cf=Csrc+v
//       5 t=Cf+v; Cf=t; Cdup=t
template<int MODE>
__global__ void k_gemm(const bf16* __restrict__ A, const bf16* __restrict__ Wt,
                       const float* __restrict__ bias, float* __restrict__ Cf,
                       bf16* __restrict__ Cb, const float* __restrict__ Csrc,
                       float* __restrict__ Cdup, int M, int N, int K, float scale) {
  __shared__ short As[128 * 64];
  __shared__ short Bs[128 * 64];
  const int tid = threadIdx.x;
  // XCD-aware bijective swizzle (m204)
  const int nwg = gridDim.x * gridDim.y;
  const int wgid = blockIdx.y * gridDim.x + blockIdx.x;
  const int q = nwg >> 3, r8 = nwg & 7;
  const int xcd = wgid & 7, loc = wgid >> 3;
  const int swz = (xcd < r8 ? xcd * (q + 1) : r8 * (q + 1) + (xcd - r8) * q) + loc;
  const int by = swz / gridDim.x, bx = swz - by * gridDim.x;
  const int m0 = by * 128, n0 = bx * 128;
  const int w = tid >> 6, l = tid & 63;
  const int wm = (w >> 1) * 64, wn = (w & 1) * 64;
  const int lr = l & 15, lk = l >> 4;
  floatx4 acc[4][4] = {};
  const short* Ash = (const short*)A;
  const short* Bsh = (const short*)Wt;
  for (int k0 = 0; k0 < K; k0 += 64) {
    for (int e = tid; e < 1024; e += 256) {
      int r = e >> 3, kg = e & 7;
      short8 v = *(const short8*)(Ash + (size_t)(m0 + r) * K + k0 + kg * 8);
      *(short8*)(&As[r * 64 + ((kg ^ (r & 7)) * 8)]) = v;
    }
    for (int e = tid; e < 1024; e += 256) {
      int r = e >> 3, kg = e & 7;
      int n = n0 + r;
      short8 v = {0, 0, 0, 0, 0, 0, 0, 0};
      if (n < N) v = *(const short8*)(Bsh + (size_t)n * K + k0 + kg * 8);
      *(short8*)(&Bs[r * 64 + ((kg ^ (r & 7)) * 8)]) = v;
    }
    __syncthreads();
    #pragma unroll
    for (int kk = 0; kk < 2; kk++) {
      short8 af[4], bfr[4];
      #pragma unroll
      for (int mi = 0; mi < 4; mi++) {
        int row = wm + mi * 16 + lr;
        int kg = kk * 4 + lk;
        af[mi] = *(const short8*)(&As[row * 64 + ((kg ^ (row & 7)) * 8)]);
      }
      #pragma unroll
      for (int ni = 0; ni < 4; ni++) {
        int row = wn + ni * 16 + lr;
        int kg = kk * 4 + lk;
        bfr[ni] = *(const short8*)(&Bs[row * 64 + ((kg ^ (row & 7)) * 8)]);
      }
      #pragma unroll
      for (int mi = 0; mi < 4; mi++)
        #pragma unroll
        for (int ni = 0; ni < 4; ni++)
          acc[mi][ni] = __builtin_amdgcn_mfma_f32_16x16x32_bf16(af[mi], bfr[ni], acc[mi][ni], 0, 0, 0);
    }
    __syncthreads();
  }
  #pragma unroll
  for (int ni = 0; ni < 4; ni++) {
    int n = n0 + wn + ni * 16 + lr;
    if (n >= N) continue;
    float bv = bias ? bias[n] : 0.f;
    #pragma unroll
    for (int mi = 0; mi < 4; mi++) {
      int mbase = m0 + wm + mi * 16 + lk * 4;
      #pragma unroll
      for (int r = 0; r < 4; r++) {
        float v = acc[mi][ni][r] * scale + bv;
        size_t idx = (size_t)(mbase + r) * N + n;
        if (MODE == 0) Cf[idx] = v;
        else if (MODE == 1) Cf[idx] += v;
        else if (MODE == 2) Cb[idx] = __float2bfloat16(v);
        else if (MODE == 3) Cb[idx] = __float2bfloat16(fmaxf(v, 0.f));
        else if (MODE == 4) Cf[idx] = Csrc[idx] + v;
        else if (MODE == 5) { float t = Cf[idx] + v; Cf[idx] = t; Cdup[idx] = t; }
      }
    }
  }
}

// ---------------- fused OPM: pair[i, jg*32.., :] += (outer(a_i,b_j)/S) @ W + bias ----------------
// Block = (jg 0..7, i). U phase as r8. Proj phase = LDS-staged GEMM: per 64-k
// step stage 16KB W-slice into swizzled LDS, MFMAs read W from LDS. Same ks
// summation order as r8 (bit-identical). Pair residual prefetched at start.
__global__ __launch_bounds__(256) void k_opm_fused(
    const bf16* __restrict__ a_t, const bf16* __restrict__ b_t,
    const bf16* __restrict__ Wt, const float* __restrict__ bias,
    float* __restrict__ pair) {
  __shared__ short U[32 * 512];   // 32 KB
  __shared__ short Wb[128 * 64];  // 16 KB, one 64-k slice of W
  const int i = blockIdx.y;
  const int jg = blockIdx.x; // 0..7
  const int tid = threadIdx.x;
  const int w = tid >> 6, l = tid & 63;
  const int lr = l & 15, lk = l >> 4;
  const short* at = (const short*)a_t;
  const short* bt = (const short*)b_t;
  const short* wt = (const short*)Wt;

  // pair residual prefetch (block-exclusive slice)
  float pold[2][2][4];
  #pragma unroll
  for (int ntl = 0; ntl < 2; ntl++) {
    int d = (w * 2 + ntl) * 16 + lr;
    #pragma unroll
    for (int mt = 0; mt < 2; mt++)
      #pragma unroll
      for (int r = 0; r < 4; r++) {
        int j = jg * 32 + mt * 16 + lk * 4 + r;
        pold[ntl][mt][r] = pair[((size_t)i * L_ + j) * DP_ + d];
      }
  }

  short8 af[2][2];
  #pragma unroll
  for (int kh = 0; kh < 2; kh++)
    #pragma unroll
    for (int ks = 0; ks < 2; ks++)
      af[kh][ks] = *(const short8*)(at + ((size_t)i * 32 + kh * 16 + lr) * 64 + ks * 32 + lk * 8);

  floatx4 pacc[2][2] = {};
  #pragma unroll
  for (int kh = 0; kh < 2; kh++) {
    // ---- U phase for c-half kh ----
    #pragma unroll
    for (int sc = 0; sc < 2; sc++) {
      floatx4 uacc[8] = {};
      const size_t rowbase = ((size_t)(jg * 32 + sc * 16) << 5) + w * 128;
      #pragma unroll
      for (int ks = 0; ks < 2; ks++)
        #pragma unroll
        for (int nt = 0; nt < 8; nt++) {
          short8 bfr = *(const short8*)(bt + (rowbase + nt * 16 + lr) * 64 + ks * 32 + lk * 8);
          uacc[nt] = __builtin_amdgcn_mfma_f32_16x16x32_bf16(af[kh][ks], bfr, uacc[nt], 0, 0, 0);
        }
      #pragma unroll
      for (int nt = 0; nt < 8; nt++) {
        int npos = w * 128 + nt * 16 + lr;
        int jj = sc * 16 + (npos >> 5);
        int e = npos & 31;
        int g = e * 2 + (lk >> 1);
        int off = (lk & 1) * 4;
        short4s pk;
        pk.x = f2bfs(uacc[nt][0] * 0.015625f);
        pk.y = f2bfs(uacc[nt][1] * 0.015625f);
        pk.z = f2bfs(uacc[nt][2] * 0.015625f);
        pk.w = f2bfs(uacc[nt][3] * 0.015625f);
        *(short4s*)(&U[jj * 512 + ((g ^ (jj & 7)) << 3) + off]) = pk;
      }
    }
    __syncthreads();
    // ---- proj phase: 8 steps of 64 k; W staged through LDS ----
    for (int ks8 = 0; ks8 < 8; ks8++) {
      // stage this 64-k W slice: thread covers 4x16B
      #pragma unroll
      for (int ii = 0; ii < 4; ii++) {
        int lin = tid * 4 + ii;          // 0..1023
        int d = lin >> 3, rem = lin & 7; // d row, rem = 8-short chunk in 64-k
        short8 v = *(const short8*)(wt + (size_t)d * 1024 +
                                    (ks8 * 4 + (rem >> 1)) * 32 + kh * 16 + (rem & 1) * 8);
        *(short8*)(&Wb[d * 64 + ((rem ^ (d & 7)) * 8)]) = v;
      }
      __syncthreads();
      #pragma unroll
      for (int kks = 0; kks < 2; kks++) {
        short8 afp[2];
        #pragma unroll
        for (int mt = 0; mt < 2; mt++) {
          int row = mt * 16 + lr;
          int g = (ks8 * 2 + kks) * 4 + lk;
          afp[mt] = *(const short8*)(&U[row * 512 + ((g ^ (row & 7)) << 3)]);
        }
        #pragma unroll
        for (int ntl = 0; ntl < 2; ntl++) {
          int d = (w * 2 + ntl) * 16 + lr;
          int kg = kks * 4 + lk;
          short8 bfr = *(const short8*)(&Wb[d * 64 + ((kg ^ (d & 7)) * 8)]);
          #pragma unroll
          for (int mt = 0; mt < 2; mt++)
            pacc[mt][ntl] = __builtin_amdgcn_mfma_f32_16x16x32_bf16(afp[mt], bfr, pacc[mt][ntl], 0, 0, 0);
        }
      }
      __syncthreads();
    }
  }
  // ---- write pair (residual added from prefetched values) ----
  int jbase = jg * 32;
  #pragma unroll
  for (int ntl = 0; ntl < 2; ntl++) {
    int d = (w * 2 + ntl) * 16 + lr;
    float bv = bias[d];
    #pragma unroll
    for (int mt = 0; mt < 2; mt++)
      #pragma unroll
      for (int r = 0; r < 4; r++) {
        int j = jbase + mt * 16 + lk * 4 + r;
        pair[((size_t)i * L_ + j) * DP_ + d] = pold[ntl][mt][r] + pacc[mt][ntl][r] + bv;
      }
  }
}

// ---------------- MFMA attention: one (lead, head) per block; K/V staged once;
// internal loop over 64-row Q chunks; P in own buffer -> no barriers in loop. ----------------
template<int N>
__global__ __launch_bounds__(256) void k_attn_mfma(
    const bf16* __restrict__ qkv, bf16* __restrict__ out, int dmodel,
    int tokStride, int leadStride, int otokStride, int oleadStride, float scale) {
  constexpr int NT = N / 16;   // S col-tiles per wave
  constexpr int NK = N / 32;   // PV k-steps
  constexpr int NIC = N / 64;  // Q chunks
  __shared__ short Ks[N * 32];
  __shared__ short Vt[N * 32];
  __shared__ short Qs[2048];
  __shared__ short P[64 * N];

  const int lead = blockIdx.x;
  const int h = blockIdx.y;
  const short* base = (const short*)qkv + (size_t)lead * leadStride;
  const int qoff = h * 32, koff = dmodel + h * 32, voff = 2 * dmodel + h * 32;
  const int tid = threadIdx.x;
  const int l = tid & 63, w = tid >> 6;
  const int lr = l & 15, lk = l >> 4;

  for (int e = tid; e < N * 4; e += 256) {
    int j = e >> 2, kg = e & 3;
    short8 v = *(const short8*)(base + (size_t)j * tokStride + koff + kg * 8);
    *(short8*)(&Ks[(kg * N + j) * 8]) = v;
  }
  for (int e = tid; e < N * 32; e += 256) {
    int j = e >> 5, d = e & 31;
    Vt[((j >> 5) * 4 + ((j >> 3) & 3)) * 256 + d * 8 + (j & 7)] = base[(size_t)j * tokStride + voff + d];
  }
  __syncthreads();

  for (int ic = 0; ic < NIC; ic++) {
    {
      int r = tid >> 2, kg = tid & 3;
      short8 v = *(const short8*)(base + (size_t)(ic * 64 + r) * tokStride + qoff + kg * 8);
      *(short8*)(&Qs[(kg * 64 + r) * 8]) = v;
    }
    short8 aq = *(const short8*)(&Qs[(lk * 64 + w * 16 + lr) * 8]);
    floatx4 sa[NT];
    #pragma unroll
    for (int t = 0; t < NT; t++) {
      short8 bk = *(const short8*)(&Ks[(lk * N + t * 16 + lr) * 8]);
      floatx4 z = {0.f, 0.f, 0.f, 0.f};
      sa[t] = __builtin_amdgcn_mfma_f32_16x16x32_bf16(aq, bk, z, 0, 0, 0);
    }

    float mrow[4] = {-1e30f, -1e30f, -1e30f, -1e30f};
    #pragma unroll
    for (int t = 0; t < NT; t++)
      #pragma unroll
      for (int r = 0; r < 4; r++) {
        float s = fminf(fmaxf(sa[t][r] * scale, -50.f), 50.f);
        sa[t][r] = s;
        mrow[r] = fmaxf(mrow[r], s);
      }
    #pragma unroll
    for (int o = 1; o <= 8; o <<= 1)
      #pragma unroll
      for (int r = 0; r < 4; r++) mrow[r] = fmaxf(mrow[r], __shfl_xor(mrow[r], o));
    float srow[4] = {0.f, 0.f, 0.f, 0.f};
    #pragma unroll
    for (int t = 0; t < NT; t++)
      #pragma unroll
      for (int r = 0; r < 4; r++) {
        float p = __expf(sa[t][r] - mrow[r]);
        sa[t][r] = p;
        srow[r] += p;
      }
    #pragma unroll
    for (int o = 1; o <= 8; o <<= 1)
      #pragma unroll
      for (int r = 0; r < 4; r++) srow[r] += __shfl_xor(srow[r], o);
    float inv[4];
    #pragma unroll
    for (int r = 0; r < 4; r++) inv[r] = 1.f / srow[r];

    #pragma unroll
    for (int t = 0; t < NT; t++) {
      int c = t * 16 + lr;
      int kstep = c >> 5, kslot = (c >> 3) & 3, u = c & 7;
      #pragma unroll
      for (int r = 0; r < 4; r++) {
        int row = w * 16 + lk * 4 + r;
        P[((kstep * 4 + kslot) * 64 + row) * 8 + u] = f2bfs(sa[t][r] * inv[r]);
      }
    }

    floatx4 oacc[2] = {{0.f,0.f,0.f,0.f},{0.f,0.f,0.f,0.f}};
    #pragma unroll
    for (int ks = 0; ks < NK; ks++) {
      short8 ap = *(const short8*)(&P[((ks * 4 + lk) * 64 + w * 16 + lr) * 8]);
      #pragma unroll
      for (int ct = 0; ct < 2; ct++) {
        short8 bv = *(const short8*)(&Vt[((ks * 4 + lk) * 32 + ct * 16 + lr) * 8]);
        oacc[ct] = __builtin_amdgcn_mfma_f32_16x16x32_bf16(ap, bv, oacc[ct], 0, 0, 0);
      }
    }
    bf16* ob = out + (size_t)lead * oleadStride + h * 32;
    #pragma unroll
    for (int ct = 0; ct < 2; ct++)
      #pragma unroll
      for (int r = 0; r < 4; r++) {
        int tok = ic * 64 + w * 16 + lk * 4 + r;
        ob[(size_t)tok * otokStride + ct * 16 + lr] = __float2bfloat16(oacc[ct][r]);
      }
  }
}

extern "C" void kernel_launch(void* const* d_in, const int* in_sizes, int n_in,
                              void* d_out, int out_size, void* d_ws, size_t ws_size,
                              hipStream_t stream) {
  const float* msa_in    = (const float*)d_in[0];
  const float* pair_in   = (const float*)d_in[1];
  const float* row_ng    = (const float*)d_in[2];
  const float* row_nb    = (const float*)d_in[3];
  const float* row_qkv_w = (const float*)d_in[4];
  const float* row_qkv_b = (const float*)d_in[5];
  const float* row_out_w = (const float*)d_in[6];
  const float* row_out_b = (const float*)d_in[7];
  const float* col_ng    = (const float*)d_in[8];
  const float* col_nb    = (const float*)d_in[9];
  const float* col_qkv_w = (const float*)d_in[10];
  const float* col_qkv_b = (const float*)d_in[11];
  const float* col_out_w = (const float*)d_in[12];
  const float* col_out_b = (const float*)d_in[13];
  const float* ff_ng     = (const float*)d_in[14];
  const float* ff_nb     = (const float*)d_in[15];
  const float* ff_w1     = (const float*)d_in[16];
  const float* ff_b1     = (const float*)d_in[17];
  const float* ff_w2     = (const float*)d_in[18];
  const float* ff_b2     = (const float*)d_in[19];
  const float* op_ng     = (const float*)d_in[20];
  const float* op_nb     = (const float*)d_in[21];
  const float* op_a_w    = (const float*)d_in[22];
  const float* op_a_b    = (const float*)d_in[23];
  const float* op_b_w    = (const float*)d_in[24];
  const float* op_b_b    = (const float*)d_in[25];
  const float* op_out_w  = (const float*)d_in[26];
  const float* op_out_b  = (const float*)d_in[27];
  const float* tri_ng    = (const float*)d_in[28];
  const float* tri_nb    = (const float*)d_in[29];
  const float* tri_qkv_w = (const float*)d_in[30];
  const float* tri_qkv_b = (const float*)d_in[31];
  const float* tri_out_w = (const float*)d_in[32];
  const float* tri_out_b = (const float*)d_in[33];

  const int MT = S_ * L_;   // 16384
  const int PT = L_ * L_;   // 65536

  // ---- arena (byte offsets) ----
  char* ws = (char*)d_ws;
  float* msa_f  = (float*)(ws);                    // 16 MB
  float* pair_f = (float*)(ws + 16777216);         // 32 MB
  char*  X      = ws + 50331648;                   // 48 MB scratch (qkv bf16 / ffh bf16)
  bf16*  ln_b   = (bf16*)(ws + 100663296);         // 16 MB
  bf16*  ao_b   = (bf16*)(ws + 117440512);         // 16 MB
  bf16*  a_buf  = (bf16*)(ws + 134217728);         // 1 MB
  bf16*  b_buf  = (bf16*)(ws + 135266304);         // 1 MB
  bf16*  a_t    = (bf16*)(ws + 136314880);         // 1 MB
  bf16*  b_t    = (bf16*)(ws + 137363456);         // 1 MB
  bf16*  wts    = (bf16*)(ws + 138412032);         // ~2.6 MB

  bf16* row_qkv_wt = wts;                 // 768*256
  bf16* col_qkv_wt = row_qkv_wt + 196608;
  bf16* row_out_wt = col_qkv_wt + 196608; // 256*256
  bf16* col_out_wt = row_out_wt + 65536;
  bf16* ff_w1t     = col_out_wt + 65536;  // 1024*256
  bf16* ff_w2t     = ff_w1t + 262144;     // 256*1024
  bf16* op_a_wt    = ff_w2t + 262144;     // 32*256
  bf16* op_b_wt    = op_a_wt + 8192;
  bf16* op_out_wt  = op_b_wt + 8192;      // 128*1024 (ec-permuted)
  bf16* tri_qkv_wt = op_out_wt + 131072;  // 384*128
  bf16* tri_out_wt = tri_qkv_wt + 49152;  // 128*128

  bf16* qkv_bf = (bf16*)X;   // row/col: 25MB; tri: 48MB
  bf16* ffh    = (bf16*)X;

  float* dout_msa  = (float*)d_out;
  float* dout_pair = (float*)d_out + (size_t)MT * DM_;

  const float scale = 0.17677669529663687f; // 1/sqrt(32)

  // residual streams
  (void)hipMemcpyAsync(msa_f, msa_in, (size_t)MT * DM_ * 4, hipMemcpyDeviceToDevice, stream);
  (void)hipMemcpyAsync(pair_f, pair_in, (size_t)PT * DP_ * 4, hipMemcpyDeviceToDevice, stream);

  // weight transpose+convert
  k_wt<<<dim3(256 / 32, 768 / 32), 256, 0, stream>>>(row_qkv_w, row_qkv_wt, 256, 768);
  k_wt<<<dim3(256 / 32, 768 / 32), 256, 0, stream>>>(col_qkv_w, col_qkv_wt, 256, 768);
  k_wt<<<dim3(256 / 32, 256 / 32), 256, 0, stream>>>(row_out_w, row_out_wt, 256, 256);
  k_wt<<<dim3(256 / 32, 256 / 32), 256, 0, stream>>>(col_out_w, col_out_wt, 256, 256);
  k_wt<<<dim3(256 / 32, 1024 / 32), 256, 0, stream>>>(ff_w1, ff_w1t, 256, 1024);
  k_wt<<<dim3(1024 / 32, 256 / 32), 256, 0, stream>>>(ff_w2, ff_w2t, 1024, 256);
  k_wt<<<dim3(256 / 32, 32 / 32), 256, 0, stream>>>(op_a_w, op_a_wt, 256, 32);
  k_wt<<<dim3(256 / 32, 32 / 32), 256, 0, stream>>>(op_b_w, op_b_wt, 256, 32);
  k_wtopm<<<512, 256, 0, stream>>>(op_out_w, op_out_wt);
  k_wt<<<dim3(128 / 32, 384 / 32), 256, 0, stream>>>(tri_qkv_w, tri_qkv_wt, 128, 384);
  k_wt<<<dim3(128 / 32, 128 / 32), 256, 0, stream>>>(tri_out_w, tri_out_wt, 128, 128);

  // ---- 1. row attention (attend over L) ----
  k_ln<<<MT / 4, 256, 0, stream>>>(msa_f, ln_b, row_ng, row_nb, DM_);
  k_gemm<2><<<dim3(6, 128), 256, 0, stream>>>(ln_b, row_qkv_wt, row_qkv_b, nullptr, qkv_bf, nullptr, nullptr, MT, 768, 256, 1.f);
  k_attn_mfma<256><<<dim3(S_, H_), 256, 0, stream>>>(qkv_bf, ao_b, DM_, 768, L_ * 768, DM_, L_ * DM_, scale);
  k_gemm<1><<<dim3(2, 128), 256, 0, stream>>>(ao_b, row_out_wt, row_out_b, msa_f, nullptr, nullptr, nullptr, MT, DM_, DM_, 1.f);

  // ---- 2. column attention (attend over S) ----
  k_ln<<<MT / 4, 256, 0, stream>>>(msa_f, ln_b, col_ng, col_nb, DM_);
  k_gemm<2><<<dim3(6, 128), 256, 0, stream>>>(ln_b, col_qkv_wt, col_qkv_b, nullptr, qkv_bf, nullptr, nullptr, MT, 768, 256, 1.f);
  k_attn_mfma<64><<<dim3(L_, H_), 256, 0, stream>>>(qkv_bf, ao_b, DM_, L_ * 768, 768, L_ * DM_, DM_, scale);
  k_gemm<1><<<dim3(2, 128), 256, 0, stream>>>(ao_b, col_out_wt, col_out_b, msa_f, nullptr, nullptr, nullptr, MT, DM_, DM_, 1.f);

  // ---- 3. feed-forward (down-proj also writes d_out msa) ----
  k_ln<<<MT / 4, 256, 0, stream>>>(msa_f, ln_b, ff_ng, ff_nb, DM_);
  k_gemm<3><<<dim3(8, 128), 256, 0, stream>>>(ln_b, ff_w1t, ff_b1, nullptr, ffh, nullptr, nullptr, MT, 1024, 256, 1.f);
  k_gemm<5><<<dim3(2, 128), 256, 0, stream>>>(ffh, ff_w2t, ff_b2, msa_f, nullptr, nullptr, dout_msa, MT, DM_, 1024, 1.f);

  // ---- 4. outer product mean -> pair ----
  k_ln<<<MT / 4, 256, 0, stream>>>(msa_f, ln_b, op_ng, op_nb, DM_);
  k_gemm<2><<<dim3(1, 128), 256, 0, stream>>>(ln_b, op_a_wt, op_a_b, nullptr, a_buf, nullptr, nullptr, MT, NO_, DM_, 1.f);
  k_gemm<2><<<dim3(1, 128), 256, 0, stream>>>(ln_b, op_b_wt, op_b_b, nullptr, b_buf, nullptr, nullptr, MT, NO_, DM_, 1.f);
  k_topm<<<L_, 256, 0, stream>>>(a_buf, a_t);
  k_topm<<<L_, 256, 0, stream>>>(b_buf, b_t);
  k_opm_fused<<<dim3(8, L_), 256, 0, stream>>>(a_t, b_t, op_out_wt, op_out_b, pair_f);

  // ---- 5. triangle attention (out-proj writes d_out pair directly) ----
  k_ln<<<PT / 4, 256, 0, stream>>>(pair_f, ln_b, tri_ng, tri_nb, DP_);
  k_gemm<2><<<dim3(3, 512), 256, 0, stream>>>(ln_b, tri_qkv_wt, tri_qkv_b, nullptr, qkv_bf, nullptr, nullptr, PT, 384, DP_, 1.f);
  k_attn_mfma<256><<<dim3(L_, HT_), 256, 0, stream>>>(qkv_bf, ao_b, DP_, 384, L_ * 384, DP_, L_ * DP_, scale);
  k_gemm<4><<<dim3(1, 512), 256, 0, stream>>>(ao_b, tri_out_wt, tri_out_b, dout_pair, nullptr, pair_f, nullptr, PT, DP_, DP_, 1.f);
}

// Round 12
// 523.786 us; speedup vs baseline: 1.1376x; 1.1376x over previous
//
#include <hip/hip_runtime.h>
#include <hip/hip_bf16.h>

// MSA Transformer block: B=1, S=64, L=256, DM=256, DP=128, H=8, HT=4, NO=32
// Round 12: consolidation — no input memcpys (residuals fused into GEMM/OPM),
// 10 weight-transposes fused into 1 launch, OPM a/b GEMMs+transposes merged.

#define S_ 64
#define L_ 256
#define DM_ 256
#define DP_ 128
#define H_ 8
#define HT_ 4
#define NO_ 32

typedef __hip_bfloat16 bf16;
typedef short short4s __attribute__((ext_vector_type(4)));
typedef short short8 __attribute__((ext_vector_type(8)));
typedef float floatx4 __attribute__((ext_vector_type(4)));

__device__ __forceinline__ short f2bfs(float x) {
  union { float f; unsigned u; } v;
  v.f = x;
  unsigned r = (v.u + 0x7fffu + ((v.u >> 16) & 1u)) >> 16;
  return (short)r;
}

// ---------------- layernorm (4 rows per 256-thr block, 1 wave per row) ----------------
__global__ void k_ln(const float* __restrict__ src, bf16* __restrict__ dst,
                     const float* __restrict__ g, const float* __restrict__ bta, int D) {
  int row = blockIdx.x * 4 + (threadIdx.x >> 6);
  const float* x = src + (size_t)row * D;
  bf16* y = dst + (size_t)row * D;
  int t = threadIdx.x & 63;
  float v[4];
  int cnt = 0;
  float sum = 0.f;
  for (int e = t; e < D; e += 64) { float xv = x[e]; v[cnt++] = xv; sum += xv; }
  #pragma unroll
  for (int o = 32; o; o >>= 1) sum += __shfl_down(sum, o);
  sum = __shfl(sum, 0);
  float mean = sum / D;
  float var = 0.f;
  for (int k = 0; k < cnt; k++) { float d = v[k] - mean; var += d * d; }
  #pragma unroll
  for (int o = 32; o; o >>= 1) var += __shfl_down(var, o);
  var = __shfl(var, 0);
  float rstd = rsqrtf(var / D + 1e-5f);
  cnt = 0;
  for (int e = t; e < D; e += 64)
    y[e] = __float2bfloat16((v[cnt++] - mean) * rstd * g[e] + bta[e]);
}

// ---------------- fused weight transpose: 10 jobs, one launch ----------------
struct WtJob { const float* W; bf16* Wt; int K; int N; int nblk; };
struct WtJobs { WtJob j[10]; };

__global__ void k_wt_all(WtJobs jobs) {
  __shared__ float tile[32][33];
  int b = blockIdx.x;
  int ji = 0;
  while (ji < 9 && b >= jobs.j[ji].nblk) { b -= jobs.j[ji].nblk; ji++; }
  const float* W = jobs.j[ji].W;
  bf16* Wt = jobs.j[ji].Wt;
  int K = jobs.j[ji].K, N = jobs.j[ji].N;
  int kt = K >> 5;
  int k0 = (b % kt) * 32, n0 = (b / kt) * 32;
  int tid = threadIdx.x; // 256
  for (int e = tid; e < 1024; e += 256) {
    int r = e >> 5, c = e & 31;
    tile[r][c] = W[(size_t)(k0 + r) * N + (n0 + c)];
  }
  __syncthreads();
  for (int e = tid; e < 1024; e += 256) {
    int r = e >> 5, c = e & 31;
    Wt[(size_t)(n0 + r) * K + (k0 + c)] = __float2bfloat16(tile[c][r]);
  }
}

// ---------------- OPM proj weight permute + ab-bias concat ----------------
__global__ void k_wtopm(const float* __restrict__ W, bf16* __restrict__ Wt,
                        const float* __restrict__ ba, const float* __restrict__ bb,
                        float* __restrict__ bias_ab) {
  if (blockIdx.x == 0 && threadIdx.x < 64)
    bias_ab[threadIdx.x] = threadIdx.x < 32 ? ba[threadIdx.x] : bb[threadIdx.x - 32];
  int idx = blockIdx.x * 256 + threadIdx.x; // 131072
  int d = idx >> 10, kk = idx & 1023;
  int e = kk >> 5, c = kk & 31;
  Wt[idx] = __float2bfloat16(W[(size_t)(c * 32 + e) * 128 + d]);
}

// ---------------- OPM transpose: ab_buf[(s*L+i)*64 + y*32 + c] -> {a_t|b_t}[(i*32+c)*64+s] ----------------
__global__ void k_topm(const bf16* __restrict__ ab, bf16* __restrict__ a_t,
                       bf16* __restrict__ b_t) {
  __shared__ bf16 tile[64][34];
  int i = blockIdx.x;       // L_
  int y = blockIdx.y;       // 0 = a, 1 = b
  bf16* out = y ? b_t : a_t;
  int tid = threadIdx.x; // 256
  for (int e = tid; e < 64 * 32; e += 256) {
    int s = e >> 5, c = e & 31;
    tile[s][c] = ab[((size_t)s * L_ + i) * 64 + y * 32 + c];
  }
  __syncthreads();
  for (int e = tid; e < 64 * 32; e += 256) {
    int c = e >> 6, s = e & 63;
    out[((size_t)i * NO_ + c) * S_ + s] = tile[s][c];
  }
}

// ---------------- bf16 MFMA GEMM ----------------
// MODE: 0 Cf=v | 1 Cf+=v | 2 Cb=bf16(v) | 3 Cb=bf16(relu v) | 4 Cf=Csrc+v
//       5 t=Cf+v; Cf=t; Cdup=t
template<int MODE>
__global__ void k_gemm(const bf16* __restrict__ A, const bf16* __restrict__ Wt,
                       const float* __restrict__ bias, float* __restrict__ Cf,
                       bf16* __restrict__ Cb, const float* __restrict__ Csrc,
                       float* __restrict__ Cdup, int M, int N, int K, float scale) {
  __shared__ short As[128 * 64];
  __shared__ short Bs[128 * 64];
  const int tid = threadIdx.x;
  // XCD-aware bijective swizzle (m204)
  const int nwg = gridDim.x * gridDim.y;
  const int wgid = blockIdx.y * gridDim.x + blockIdx.x;
  const int q = nwg >> 3, r8 = nwg & 7;
  const int xcd = wgid & 7, loc = wgid >> 3;
  const int swz = (xcd < r8 ? xcd * (q + 1) : r8 * (q + 1) + (xcd - r8) * q) + loc;
  const int by = swz / gridDim.x, bx = swz - by * gridDim.x;
  const int m0 = by * 128, n0 = bx * 128;
  const int w = tid >> 6, l = tid & 63;
  const int wm = (w >> 1) * 64, wn = (w & 1) * 64;
  const int lr = l & 15, lk = l >> 4;
  floatx4 acc[4][4] = {};
  const short* Ash = (const short*)A;
  const short* Bsh = (const short*)Wt;
  for (int k0 = 0; k0 < K; k0 += 64) {
    for (int e = tid; e < 1024; e += 256) {
      int r = e >> 3, kg = e & 7;
      short8 v = *(const short8*)(Ash + (size_t)(m0 + r) * K + k0 + kg * 8);
      *(short8*)(&As[r * 64 + ((kg ^ (r & 7)) * 8)]) = v;
    }
    for (int e = tid; e < 1024; e += 256) {
      int r = e >> 3, kg = e & 7;
      int n = n0 + r;
      short8 v = {0, 0, 0, 0, 0, 0, 0, 0};
      if (n < N) v = *(const short8*)(Bsh + (size_t)n * K + k0 + kg * 8);
      *(short8*)(&Bs[r * 64 + ((kg ^ (r & 7)) * 8)]) = v;
    }
    __syncthreads();
    #pragma unroll
    for (int kk = 0; kk < 2; kk++) {
      short8 af[4], bfr[4];
      #pragma unroll
      for (int mi = 0; mi < 4; mi++) {
        int row = wm + mi * 16 + lr;
        int kg = kk * 4 + lk;
        af[mi] = *(const short8*)(&As[row * 64 + ((kg ^ (row & 7)) * 8)]);
      }
      #pragma unroll
      for (int ni = 0; ni < 4; ni++) {
        int row = wn + ni * 16 + lr;
        int kg = kk * 4 + lk;
        bfr[ni] = *(const short8*)(&Bs[row * 64 + ((kg ^ (row & 7)) * 8)]);
      }
      #pragma unroll
      for (int mi = 0; mi < 4; mi++)
        #pragma unroll
        for (int ni = 0; ni < 4; ni++)
          acc[mi][ni] = __builtin_amdgcn_mfma_f32_16x16x32_bf16(af[mi], bfr[ni], acc[mi][ni], 0, 0, 0);
    }
    __syncthreads();
  }
  #pragma unroll
  for (int ni = 0; ni < 4; ni++) {
    int n = n0 + wn + ni * 16 + lr;
    if (n >= N) continue;
    float bv = bias ? bias[n] : 0.f;
    #pragma unroll
    for (int mi = 0; mi < 4; mi++) {
      int mbase = m0 + wm + mi * 16 + lk * 4;
      #pragma unroll
      for (int r = 0; r < 4; r++) {
        float v = acc[mi][ni][r] * scale + bv;
        size_t idx = (size_t)(mbase + r) * N + n;
        if (MODE == 0) Cf[idx] = v;
        else if (MODE == 1) Cf[idx] += v;
        else if (MODE == 2) Cb[idx] = __float2bfloat16(v);
        else if (MODE == 3) Cb[idx] = __float2bfloat16(fmaxf(v, 0.f));
        else if (MODE == 4) Cf[idx] = Csrc[idx] + v;
        else if (MODE == 5) { float t = Cf[idx] + v; Cf[idx] = t; Cdup[idx] = t; }
      }
    }
  }
}

// ---------------- fused OPM (r8 body): pair_out = pair_in + (outer/S)@W + bias ----------------
__global__ __launch_bounds__(256) void k_opm_fused(
    const bf16* __restrict__ a_t, const bf16* __restrict__ b_t,
    const bf16* __restrict__ Wt, const float* __restrict__ bias,
    const float* __restrict__ pair_in, float* __restrict__ pair_out) {
  __shared__ short U[32 * 512]; // 32 KB
  const int i = blockIdx.y;
  const int jg = blockIdx.x; // 0..7
  const int tid = threadIdx.x;
  const int w = tid >> 6, l = tid & 63;
  const int lr = l & 15, lk = l >> 4;
  const short* at = (const short*)a_t;
  const short* bt = (const short*)b_t;
  const short* wt = (const short*)Wt;

  short8 af[2][2];
  #pragma unroll
  for (int kh = 0; kh < 2; kh++)
    #pragma unroll
    for (int ks = 0; ks < 2; ks++)
      af[kh][ks] = *(const short8*)(at + ((size_t)i * 32 + kh * 16 + lr) * 64 + ks * 32 + lk * 8);

  floatx4 pacc[2][2] = {};
  #pragma unroll
  for (int kh = 0; kh < 2; kh++) {
    #pragma unroll
    for (int sc = 0; sc < 2; sc++) {
      floatx4 uacc[8] = {};
      const size_t rowbase = ((size_t)(jg * 32 + sc * 16) << 5) + w * 128;
      #pragma unroll
      for (int ks = 0; ks < 2; ks++)
        #pragma unroll
        for (int nt = 0; nt < 8; nt++) {
          short8 bfr = *(const short8*)(bt + (rowbase + nt * 16 + lr) * 64 + ks * 32 + lk * 8);
          uacc[nt] = __builtin_amdgcn_mfma_f32_16x16x32_bf16(af[kh][ks], bfr, uacc[nt], 0, 0, 0);
        }
      #pragma unroll
      for (int nt = 0; nt < 8; nt++) {
        int npos = w * 128 + nt * 16 + lr;
        int jj = sc * 16 + (npos >> 5);
        int e = npos & 31;
        int g = e * 2 + (lk >> 1);
        int off = (lk & 1) * 4;
        short4s pk;
        pk.x = f2bfs(uacc[nt][0] * 0.015625f);
        pk.y = f2bfs(uacc[nt][1] * 0.015625f);
        pk.z = f2bfs(uacc[nt][2] * 0.015625f);
        pk.w = f2bfs(uacc[nt][3] * 0.015625f);
        *(short4s*)(&U[jj * 512 + ((g ^ (jj & 7)) << 3) + off]) = pk;
      }
    }
    __syncthreads();
    #pragma unroll 4
    for (int ks = 0; ks < 16; ks++) {
      short8 afp[2];
      #pragma unroll
      for (int mt = 0; mt < 2; mt++) {
        int row = mt * 16 + lr;
        int g = ks * 4 + lk;
        afp[mt] = *(const short8*)(&U[row * 512 + ((g ^ (row & 7)) << 3)]);
      }
      int wko = (ks * 2 + (lk >> 1)) * 32 + kh * 16 + (lk & 1) * 8;
      #pragma unroll
      for (int ntl = 0; ntl < 2; ntl++) {
        int d = (w * 2 + ntl) * 16 + lr;
        short8 bfr = *(const short8*)(wt + (size_t)d * 1024 + wko);
        #pragma unroll
        for (int mt = 0; mt < 2; mt++)
          pacc[mt][ntl] = __builtin_amdgcn_mfma_f32_16x16x32_bf16(afp[mt], bfr, pacc[mt][ntl], 0, 0, 0);
      }
    }
    __syncthreads();
  }
  int jbase = jg * 32;
  #pragma unroll
  for (int ntl = 0; ntl < 2; ntl++) {
    int d = (w * 2 + ntl) * 16 + lr;
    float bv = bias[d];
    #pragma unroll
    for (int mt = 0; mt < 2; mt++)
      #pragma unroll
      for (int r = 0; r < 4; r++) {
        int j = jbase + mt * 16 + lk * 4 + r;
        size_t idx = ((size_t)i * L_ + j) * DP_ + d;
        pair_out[idx] = pair_in[idx] + pacc[mt][ntl][r] + bv;
      }
  }
}

// ---------------- MFMA attention: one (lead, head) per block; K/V staged once ----------------
template<int N>
__global__ __launch_bounds__(256) void k_attn_mfma(
    const bf16* __restrict__ qkv, bf16* __restrict__ out, int dmodel,
    int tokStride, int leadStride, int otokStride, int oleadStride, float scale) {
  constexpr int NT = N / 16;
  constexpr int NK = N / 32;
  constexpr int NIC = N / 64;
  __shared__ short Ks[N * 32];
  __shared__ short Vt[N * 32];
  __shared__ short Qs[2048];
  __shared__ short P[64 * N];

  const int lead = blockIdx.x;
  const int h = blockIdx.y;
  const short* base = (const short*)qkv + (size_t)lead * leadStride;
  const int qoff = h * 32, koff = dmodel + h * 32, voff = 2 * dmodel + h * 32;
  const int tid = threadIdx.x;
  const int l = tid & 63, w = tid >> 6;
  const int lr = l & 15, lk = l >> 4;

  for (int e = tid; e < N * 4; e += 256) {
    int j = e >> 2, kg = e & 3;
    short8 v = *(const short8*)(base + (size_t)j * tokStride + koff + kg * 8);
    *(short8*)(&Ks[(kg * N + j) * 8]) = v;
  }
  for (int e = tid; e < N * 32; e += 256) {
    int j = e >> 5, d = e & 31;
    Vt[((j >> 5) * 4 + ((j >> 3) & 3)) * 256 + d * 8 + (j & 7)] = base[(size_t)j * tokStride + voff + d];
  }
  __syncthreads();

  for (int ic = 0; ic < NIC; ic++) {
    {
      int r = tid >> 2, kg = tid & 3;
      short8 v = *(const short8*)(base + (size_t)(ic * 64 + r) * tokStride + qoff + kg * 8);
      *(short8*)(&Qs[(kg * 64 + r) * 8]) = v;
    }
    short8 aq = *(const short8*)(&Qs[(lk * 64 + w * 16 + lr) * 8]);
    floatx4 sa[NT];
    #pragma unroll
    for (int t = 0; t < NT; t++) {
      short8 bk = *(const short8*)(&Ks[(lk * N + t * 16 + lr) * 8]);
      floatx4 z = {0.f, 0.f, 0.f, 0.f};
      sa[t] = __builtin_amdgcn_mfma_f32_16x16x32_bf16(aq, bk, z, 0, 0, 0);
    }

    float mrow[4] = {-1e30f, -1e30f, -1e30f, -1e30f};
    #pragma unroll
    for (int t = 0; t < NT; t++)
      #pragma unroll
      for (int r = 0; r < 4; r++) {
        float s = fminf(fmaxf(sa[t][r] * scale, -50.f), 50.f);
        sa[t][r] = s;
        mrow[r] = fmaxf(mrow[r], s);
      }
    #pragma unroll
    for (int o = 1; o <= 8; o <<= 1)
      #pragma unroll
      for (int r = 0; r < 4; r++) mrow[r] = fmaxf(mrow[r], __shfl_xor(mrow[r], o));
    float srow[4] = {0.f, 0.f, 0.f, 0.f};
    #pragma unroll
    for (int t = 0; t < NT; t++)
      #pragma unroll
      for (int r = 0; r < 4; r++) {
        float p = __expf(sa[t][r] - mrow[r]);
        sa[t][r] = p;
        srow[r] += p;
      }
    #pragma unroll
    for (int o = 1; o <= 8; o <<= 1)
      #pragma unroll
      for (int r = 0; r < 4; r++) srow[r] += __shfl_xor(srow[r], o);
    float inv[4];
    #pragma unroll
    for (int r = 0; r < 4; r++) inv[r] = 1.f / srow[r];

    #pragma unroll
    for (int t = 0; t < NT; t++) {
      int c = t * 16 + lr;
      int kstep = c >> 5, kslot = (c >> 3) & 3, u = c & 7;
      #pragma unroll
      for (int r = 0; r < 4; r++) {
        int row = w * 16 + lk * 4 + r;
        P[((kstep * 4 + kslot) * 64 + row) * 8 + u] = f2bfs(sa[t][r] * inv[r]);
      }
    }

    floatx4 oacc[2] = {{0.f,0.f,0.f,0.f},{0.f,0.f,0.f,0.f}};
    #pragma unroll
    for (int ks = 0; ks < NK; ks++) {
      short8 ap = *(const short8*)(&P[((ks * 4 + lk) * 64 + w * 16 + lr) * 8]);
      #pragma unroll
      for (int ct = 0; ct < 2; ct++) {
        short8 bv = *(const short8*)(&Vt[((ks * 4 + lk) * 32 + ct * 16 + lr) * 8]);
        oacc[ct] = __builtin_amdgcn_mfma_f32_16x16x32_bf16(ap, bv, oacc[ct], 0, 0, 0);
      }
    }
    bf16* ob = out + (size_t)lead * oleadStride + h * 32;
    #pragma unroll
    for (int ct = 0; ct < 2; ct++)
      #pragma unroll
      for (int r = 0; r < 4; r++) {
        int tok = ic * 64 + w * 16 + lk * 4 + r;
        ob[(size_t)tok * otokStride + ct * 16 + lr] = __float2bfloat16(oacc[ct][r]);
      }
  }
}

extern "C" void kernel_launch(void* const* d_in, const int* in_sizes, int n_in,
                              void* d_out, int out_size, void* d_ws, size_t ws_size,
                              hipStream_t stream) {
  const float* msa_in    = (const float*)d_in[0];
  const float* pair_in   = (const float*)d_in[1];
  const float* row_ng    = (const float*)d_in[2];
  const float* row_nb    = (const float*)d_in[3];
  const float* row_qkv_w = (const float*)d_in[4];
  const float* row_qkv_b = (const float*)d_in[5];
  const float* row_out_w = (const float*)d_in[6];
  const float* row_out_b = (const float*)d_in[7];
  const float* col_ng    = (const float*)d_in[8];
  const float* col_nb    = (const float*)d_in[9];
  const float* col_qkv_w = (const float*)d_in[10];
  const float* col_qkv_b = (const float*)d_in[11];
  const float* col_out_w = (const float*)d_in[12];
  const float* col_out_b = (const float*)d_in[13];
  const float* ff_ng     = (const float*)d_in[14];
  const float* ff_nb     = (const float*)d_in[15];
  const float* ff_w1     = (const float*)d_in[16];
  const float* ff_b1     = (const float*)d_in[17];
  const float* ff_w2     = (const float*)d_in[18];
  const float* ff_b2     = (const float*)d_in[19];
  const float* op_ng     = (const float*)d_in[20];
  const float* op_nb     = (const float*)d_in[21];
  const float* op_a_w    = (const float*)d_in[22];
  const float* op_a_b    = (const float*)d_in[23];
  const float* op_b_w    = (const float*)d_in[24];
  const float* op_b_b    = (const float*)d_in[25];
  const float* op_out_w  = (const float*)d_in[26];
  const float* op_out_b  = (const float*)d_in[27];
  const float* tri_ng    = (const float*)d_in[28];
  const float* tri_nb    = (const float*)d_in[29];
  const float* tri_qkv_w = (const float*)d_in[30];
  const float* tri_qkv_b = (const float*)d_in[31];
  const float* tri_out_w = (const float*)d_in[32];
  const float* tri_out_b = (const float*)d_in[33];

  const int MT = S_ * L_;   // 16384
  const int PT = L_ * L_;   // 65536

  // ---- arena (byte offsets) ----
  char* ws = (char*)d_ws;
  float* msa_f  = (float*)(ws);                    // 16 MB
  float* pair_f = (float*)(ws + 16777216);         // 32 MB
  char*  X      = ws + 50331648;                   // 48 MB scratch (qkv bf16 / ffh bf16)
  bf16*  ln_b   = (bf16*)(ws + 100663296);         // 16 MB
  bf16*  ao_b   = (bf16*)(ws + 117440512);         // 16 MB
  bf16*  ab_buf = (bf16*)(ws + 134217728);         // 2 MB (MT x 64)
  bf16*  a_t    = (bf16*)(ws + 136314880);         // 1 MB
  bf16*  b_t    = (bf16*)(ws + 137363456);         // 1 MB
  bf16*  wts    = (bf16*)(ws + 138412032);         // ~2.6 MB
  float* bias_ab = (float*)(ws + 141557760);       // 64 floats

  bf16* row_qkv_wt = wts;                 // 768*256
  bf16* col_qkv_wt = row_qkv_wt + 196608;
  bf16* row_out_wt = col_qkv_wt + 196608; // 256*256
  bf16* col_out_wt = row_out_wt + 65536;
  bf16* ff_w1t     = col_out_wt + 65536;  // 1024*256
  bf16* ff_w2t     = ff_w1t + 262144;     // 256*1024
  bf16* op_ab_wt   = ff_w2t + 262144;     // 64*256
  bf16* op_out_wt  = op_ab_wt + 16384;    // 128*1024 (ec-permuted)
  bf16* tri_qkv_wt = op_out_wt + 131072;  // 384*128
  bf16* tri_out_wt = tri_qkv_wt + 49152;  // 128*128

  bf16* qkv_bf = (bf16*)X;   // row/col: 25MB; tri: 48MB
  bf16* ffh    = (bf16*)X;

  float* dout_msa  = (float*)d_out;
  float* dout_pair = (float*)d_out + (size_t)MT * DM_;

  const float scale = 0.17677669529663687f; // 1/sqrt(32)

  // ---- weight prep: 2 launches total ----
  WtJobs jobs;
  jobs.j[0] = {row_qkv_w, row_qkv_wt, 256, 768, 192};
  jobs.j[1] = {col_qkv_w, col_qkv_wt, 256, 768, 192};
  jobs.j[2] = {row_out_w, row_out_wt, 256, 256, 64};
  jobs.j[3] = {col_out_w, col_out_wt, 256, 256, 64};
  jobs.j[4] = {ff_w1, ff_w1t, 256, 1024, 256};
  jobs.j[5] = {ff_w2, ff_w2t, 1024, 256, 256};
  jobs.j[6] = {op_a_w, op_ab_wt, 256, 32, 8};
  jobs.j[7] = {op_b_w, op_ab_wt + 32 * 256, 256, 32, 8};
  jobs.j[8] = {tri_qkv_w, tri_qkv_wt, 128, 384, 48};
  jobs.j[9] = {tri_out_w, tri_out_wt, 128, 128, 16};
  k_wt_all<<<1104, 256, 0, stream>>>(jobs);
  k_wtopm<<<512, 256, 0, stream>>>(op_out_w, op_out_wt, op_a_b, op_b_b, bias_ab);

  // ---- 1. row attention (attend over L); out-proj fuses msa residual init ----
  k_ln<<<MT / 4, 256, 0, stream>>>(msa_in, ln_b, row_ng, row_nb, DM_);
  k_gemm<2><<<dim3(6, 128), 256, 0, stream>>>(ln_b, row_qkv_wt, row_qkv_b, nullptr, qkv_bf, nullptr, nullptr, MT, 768, 256, 1.f);
  k_attn_mfma<256><<<dim3(S_, H_), 256, 0, stream>>>(qkv_bf, ao_b, DM_, 768, L_ * 768, DM_, L_ * DM_, scale);
  k_gemm<4><<<dim3(2, 128), 256, 0, stream>>>(ao_b, row_out_wt, row_out_b, msa_f, nullptr, msa_in, nullptr, MT, DM_, DM_, 1.f);

  // ---- 2. column attention (attend over S) ----
  k_ln<<<MT / 4, 256, 0, stream>>>(msa_f, ln_b, col_ng, col_nb, DM_);
  k_gemm<2><<<dim3(6, 128), 256, 0, stream>>>(ln_b, col_qkv_wt, col_qkv_b, nullptr, qkv_bf, nullptr, nullptr, MT, 768, 256, 1.f);
  k_attn_mfma<64><<<dim3(L_, H_), 256, 0, stream>>>(qkv_bf, ao_b, DM_, L_ * 768, 768, L_ * DM_, DM_, scale);
  k_gemm<1><<<dim3(2, 128), 256, 0, stream>>>(ao_b, col_out_wt, col_out_b, msa_f, nullptr, nullptr, nullptr, MT, DM_, DM_, 1.f);

  // ---- 3. feed-forward (down-proj also writes d_out msa) ----
  k_ln<<<MT / 4, 256, 0, stream>>>(msa_f, ln_b, ff_ng, ff_nb, DM_);
  k_gemm<3><<<dim3(8, 128), 256, 0, stream>>>(ln_b, ff_w1t, ff_b1, nullptr, ffh, nullptr, nullptr, MT, 1024, 256, 1.f);
  k_gemm<5><<<dim3(2, 128), 256, 0, stream>>>(ffh, ff_w2t, ff_b2, msa_f, nullptr, nullptr, dout_msa, MT, DM_, 1024, 1.f);

  // ---- 4. outer product mean -> pair (reads pair_in residual; writes pair_f) ----
  k_ln<<<MT / 4, 256, 0, stream>>>(msa_f, ln_b, op_ng, op_nb, DM_);
  k_gemm<2><<<dim3(1, 128), 256, 0, stream>>>(ln_b, op_ab_wt, bias_ab, nullptr, ab_buf, nullptr, nullptr, MT, 64, DM_, 1.f);
  k_topm<<<dim3(L_, 2), 256, 0, stream>>>(ab_buf, a_t, b_t);
  k_opm_fused<<<dim3(8, L_), 256, 0, stream>>>(a_t, b_t, op_out_wt, op_out_b, pair_in, pair_f);

  // ---- 5. triangle attention (out-proj writes d_out pair directly) ----
  k_ln<<<PT / 4, 256, 0, stream>>>(pair_f, ln_b, tri_ng, tri_nb, DP_);
  k_gemm<2><<<dim3(3, 512), 256, 0, stream>>>(ln_b, tri_qkv_wt, tri_qkv_b, nullptr, qkv_bf, nullptr, nullptr, PT, 384, DP_, 1.f);
  k_attn_mfma<256><<<dim3(L_, HT_), 256, 0, stream>>>(qkv_bf, ao_b, DP_, 384, L_ * 384, DP_, L_ * DP_, scale);
  k_gemm<4><<<dim3(1, 512), 256, 0, stream>>>(ao_b, tri_out_wt, tri_out_b, dout_pair, nullptr, pair_f, nullptr, PT, DP_, DP_, 1.f);
}

// Round 13
// 484.038 us; speedup vs baseline: 1.2310x; 1.0821x over previous
//
#include <hip/hip_runtime.h>
#include <hip/hip_bf16.h>

// MSA Transformer block: B=1, S=64, L=256, DM=256, DP=128, H=8, HT=4, NO=32
// Round 13: k_gemm64 (64x64 tile) for small-N GEMMs (4-8x grid parallelism);
// OPM software-pipelined (U(kh+1) compute overlaps proj(kh)).

#define S_ 64
#define L_ 256
#define DM_ 256
#define DP_ 128
#define H_ 8
#define HT_ 4
#define NO_ 32

typedef __hip_bfloat16 bf16;
typedef short short4s __attribute__((ext_vector_type(4)));
typedef short short8 __attribute__((ext_vector_type(8)));
typedef float floatx4 __attribute__((ext_vector_type(4)));

__device__ __forceinline__ short f2bfs(float x) {
  union { float f; unsigned u; } v;
  v.f = x;
  unsigned r = (v.u + 0x7fffu + ((v.u >> 16) & 1u)) >> 16;
  return (short)r;
}

// ---------------- layernorm (4 rows per 256-thr block, 1 wave per row) ----------------
__global__ void k_ln(const float* __restrict__ src, bf16* __restrict__ dst,
                     const float* __restrict__ g, const float* __restrict__ bta, int D) {
  int row = blockIdx.x * 4 + (threadIdx.x >> 6);
  const float* x = src + (size_t)row * D;
  bf16* y = dst + (size_t)row * D;
  int t = threadIdx.x & 63;
  float v[4];
  int cnt = 0;
  float sum = 0.f;
  for (int e = t; e < D; e += 64) { float xv = x[e]; v[cnt++] = xv; sum += xv; }
  #pragma unroll
  for (int o = 32; o; o >>= 1) sum += __shfl_down(sum, o);
  sum = __shfl(sum, 0);
  float mean = sum / D;
  float var = 0.f;
  for (int k = 0; k < cnt; k++) { float d = v[k] - mean; var += d * d; }
  #pragma unroll
  for (int o = 32; o; o >>= 1) var += __shfl_down(var, o);
  var = __shfl(var, 0);
  float rstd = rsqrtf(var / D + 1e-5f);
  cnt = 0;
  for (int e = t; e < D; e += 64)
    y[e] = __float2bfloat16((v[cnt++] - mean) * rstd * g[e] + bta[e]);
}

// ---------------- fused weight transpose: 10 jobs, one launch ----------------
struct WtJob { const float* W; bf16* Wt; int K; int N; int nblk; };
struct WtJobs { WtJob j[10]; };

__global__ void k_wt_all(WtJobs jobs) {
  __shared__ float tile[32][33];
  int b = blockIdx.x;
  int ji = 0;
  while (ji < 9 && b >= jobs.j[ji].nblk) { b -= jobs.j[ji].nblk; ji++; }
  const float* W = jobs.j[ji].W;
  bf16* Wt = jobs.j[ji].Wt;
  int K = jobs.j[ji].K, N = jobs.j[ji].N;
  int kt = K >> 5;
  int k0 = (b % kt) * 32, n0 = (b / kt) * 32;
  int tid = threadIdx.x; // 256
  for (int e = tid; e < 1024; e += 256) {
    int r = e >> 5, c = e & 31;
    tile[r][c] = W[(size_t)(k0 + r) * N + (n0 + c)];
  }
  __syncthreads();
  for (int e = tid; e < 1024; e += 256) {
    int r = e >> 5, c = e & 31;
    Wt[(size_t)(n0 + r) * K + (k0 + c)] = __float2bfloat16(tile[c][r]);
  }
}

// ---------------- OPM proj weight permute + ab-bias concat ----------------
__global__ void k_wtopm(const float* __restrict__ W, bf16* __restrict__ Wt,
                        const float* __restrict__ ba, const float* __restrict__ bb,
                        float* __restrict__ bias_ab) {
  if (blockIdx.x == 0 && threadIdx.x < 64)
    bias_ab[threadIdx.x] = threadIdx.x < 32 ? ba[threadIdx.x] : bb[threadIdx.x - 32];
  int idx = blockIdx.x * 256 + threadIdx.x; // 131072
  int d = idx >> 10, kk = idx & 1023;
  int e = kk >> 5, c = kk & 31;
  Wt[idx] = __float2bfloat16(W[(size_t)(c * 32 + e) * 128 + d]);
}

// ---------------- OPM transpose ----------------
__global__ void k_topm(const bf16* __restrict__ ab, bf16* __restrict__ a_t,
                       bf16* __restrict__ b_t) {
  __shared__ bf16 tile[64][34];
  int i = blockIdx.x;       // L_
  int y = blockIdx.y;       // 0 = a, 1 = b
  bf16* out = y ? b_t : a_t;
  int tid = threadIdx.x; // 256
  for (int e = tid; e < 64 * 32; e += 256) {
    int s = e >> 5, c = e & 31;
    tile[s][c] = ab[((size_t)s * L_ + i) * 64 + y * 32 + c];
  }
  __syncthreads();
  for (int e = tid; e < 64 * 32; e += 256) {
    int c = e >> 6, s = e & 63;
    out[((size_t)i * NO_ + c) * S_ + s] = tile[s][c];
  }
}

// ---------------- bf16 MFMA GEMM, 128x128 tile ----------------
// MODE: 0 Cf=v | 1 Cf+=v | 2 Cb=bf16(v) | 3 Cb=bf16(relu v) | 4 Cf=Csrc+v
//       5 t=Cf+v; Cf=t; Cdup=t
template<int MODE>
__global__ void k_gemm(const bf16* __restrict__ A, const bf16* __restrict__ Wt,
                       const float* __restrict__ bias, float* __restrict__ Cf,
                       bf16* __restrict__ Cb, const float* __restrict__ Csrc,
                       float* __restrict__ Cdup, int M, int N, int K, float scale) {
  __shared__ short As[128 * 64];
  __shared__ short Bs[128 * 64];
  const int tid = threadIdx.x;
  const int nwg = gridDim.x * gridDim.y;
  const int wgid = blockIdx.y * gridDim.x + blockIdx.x;
  const int q = nwg >> 3, r8 = nwg & 7;
  const int xcd = wgid & 7, loc = wgid >> 3;
  const int swz = (xcd < r8 ? xcd * (q + 1) : r8 * (q + 1) + (xcd - r8) * q) + loc;
  const int by = swz / gridDim.x, bx = swz - by * gridDim.x;
  const int m0 = by * 128, n0 = bx * 128;
  const int w = tid >> 6, l = tid & 63;
  const int wm = (w >> 1) * 64, wn = (w & 1) * 64;
  const int lr = l & 15, lk = l >> 4;
  floatx4 acc[4][4] = {};
  const short* Ash = (const short*)A;
  const short* Bsh = (const short*)Wt;
  for (int k0 = 0; k0 < K; k0 += 64) {
    for (int e = tid; e < 1024; e += 256) {
      int r = e >> 3, kg = e & 7;
      short8 v = *(const short8*)(Ash + (size_t)(m0 + r) * K + k0 + kg * 8);
      *(short8*)(&As[r * 64 + ((kg ^ (r & 7)) * 8)]) = v;
    }
    for (int e = tid; e < 1024; e += 256) {
      int r = e >> 3, kg = e & 7;
      int n = n0 + r;
      short8 v = {0, 0, 0, 0, 0, 0, 0, 0};
      if (n < N) v = *(const short8*)(Bsh + (size_t)n * K + k0 + kg * 8);
      *(short8*)(&Bs[r * 64 + ((kg ^ (r & 7)) * 8)]) = v;
    }
    __syncthreads();
    #pragma unroll
    for (int kk = 0; kk < 2; kk++) {
      short8 af[4], bfr[4];
      #pragma unroll
      for (int mi = 0; mi < 4; mi++) {
        int row = wm + mi * 16 + lr;
        int kg = kk * 4 + lk;
        af[mi] = *(const short8*)(&As[row * 64 + ((kg ^ (row & 7)) * 8)]);
      }
      #pragma unroll
      for (int ni = 0; ni < 4; ni++) {
        int row = wn + ni * 16 + lr;
        int kg = kk * 4 + lk;
        bfr[ni] = *(const short8*)(&Bs[row * 64 + ((kg ^ (row & 7)) * 8)]);
      }
      #pragma unroll
      for (int mi = 0; mi < 4; mi++)
        #pragma unroll
        for (int ni = 0; ni < 4; ni++)
          acc[mi][ni] = __builtin_amdgcn_mfma_f32_16x16x32_bf16(af[mi], bfr[ni], acc[mi][ni], 0, 0, 0);
    }
    __syncthreads();
  }
  #pragma unroll
  for (int ni = 0; ni < 4; ni++) {
    int n = n0 + wn + ni * 16 + lr;
    if (n >= N) continue;
    float bv = bias ? bias[n] : 0.f;
    #pragma unroll
    for (int mi = 0; mi < 4; mi++) {
      int mbase = m0 + wm + mi * 16 + lk * 4;
      #pragma unroll
      for (int r = 0; r < 4; r++) {
        float v = acc[mi][ni][r] * scale + bv;
        size_t idx = (size_t)(mbase + r) * N + n;
        if (MODE == 0) Cf[idx] = v;
        else if (MODE == 1) Cf[idx] += v;
        else if (MODE == 2) Cb[idx] = __float2bfloat16(v);
        else if (MODE == 3) Cb[idx] = __float2bfloat16(fmaxf(v, 0.f));
        else if (MODE == 4) Cf[idx] = Csrc[idx] + v;
        else if (MODE == 5) { float t = Cf[idx] + v; Cf[idx] = t; Cdup[idx] = t; }
      }
    }
  }
}

// ---------------- bf16 MFMA GEMM, 64x64 tile (small-N, high-parallelism) ----------------
template<int MODE>
__global__ void k_gemm64(const bf16* __restrict__ A, const bf16* __restrict__ Wt,
                         const float* __restrict__ bias, float* __restrict__ Cf,
                         bf16* __restrict__ Cb, const float* __restrict__ Csrc,
                         float* __restrict__ Cdup, int M, int N, int K, float scale) {
  __shared__ short As[64 * 64];
  __shared__ short Bs[64 * 64];
  const int tid = threadIdx.x;
  const int nwg = gridDim.x * gridDim.y;
  const int wgid = blockIdx.y * gridDim.x + blockIdx.x;
  const int q = nwg >> 3, r8 = nwg & 7;
  const int xcd = wgid & 7, loc = wgid >> 3;
  const int swz = (xcd < r8 ? xcd * (q + 1) : r8 * (q + 1) + (xcd - r8) * q) + loc;
  const int by = swz / gridDim.x, bx = swz - by * gridDim.x;
  const int m0 = by * 64, n0 = bx * 64;
  const int w = tid >> 6, l = tid & 63;
  const int wm = (w >> 1) * 32, wn = (w & 1) * 32;
  const int lr = l & 15, lk = l >> 4;
  floatx4 acc[2][2] = {};
  const short* Ash = (const short*)A;
  const short* Bsh = (const short*)Wt;
  for (int k0 = 0; k0 < K; k0 += 64) {
    for (int e = tid; e < 512; e += 256) {
      int r = e >> 3, kg = e & 7;
      short8 v = *(const short8*)(Ash + (size_t)(m0 + r) * K + k0 + kg * 8);
      *(short8*)(&As[r * 64 + ((kg ^ (r & 7)) * 8)]) = v;
    }
    for (int e = tid; e < 512; e += 256) {
      int r = e >> 3, kg = e & 7;
      int n = n0 + r;
      short8 v = {0, 0, 0, 0, 0, 0, 0, 0};
      if (n < N) v = *(const short8*)(Bsh + (size_t)n * K + k0 + kg * 8);
      *(short8*)(&Bs[r * 64 + ((kg ^ (r & 7)) * 8)]) = v;
    }
    __syncthreads();
    #pragma unroll
    for (int kk = 0; kk < 2; kk++) {
      short8 af[2], bfr[2];
      #pragma unroll
      for (int mi = 0; mi < 2; mi++) {
        int row = wm + mi * 16 + lr;
        int kg = kk * 4 + lk;
        af[mi] = *(const short8*)(&As[row * 64 + ((kg ^ (row & 7)) * 8)]);
      }
      #pragma unroll
      for (int ni = 0; ni < 2; ni++) {
        int row = wn + ni * 16 + lr;
        int kg = kk * 4 + lk;
        bfr[ni] = *(const short8*)(&Bs[row * 64 + ((kg ^ (row & 7)) * 8)]);
      }
      #pragma unroll
      for (int mi = 0; mi < 2; mi++)
        #pragma unroll
        for (int ni = 0; ni < 2; ni++)
          acc[mi][ni] = __builtin_amdgcn_mfma_f32_16x16x32_bf16(af[mi], bfr[ni], acc[mi][ni], 0, 0, 0);
    }
    __syncthreads();
  }
  #pragma unroll
  for (int ni = 0; ni < 2; ni++) {
    int n = n0 + wn + ni * 16 + lr;
    if (n >= N) continue;
    float bv = bias ? bias[n] : 0.f;
    #pragma unroll
    for (int mi = 0; mi < 2; mi++) {
      int mbase = m0 + wm + mi * 16 + lk * 4;
      #pragma unroll
      for (int r = 0; r < 4; r++) {
        float v = acc[mi][ni][r] * scale + bv;
        size_t idx = (size_t)(mbase + r) * N + n;
        if (MODE == 0) Cf[idx] = v;
        else if (MODE == 1) Cf[idx] += v;
        else if (MODE == 2) Cb[idx] = __float2bfloat16(v);
        else if (MODE == 3) Cb[idx] = __float2bfloat16(fmaxf(v, 0.f));
        else if (MODE == 4) Cf[idx] = Csrc[idx] + v;
        else if (MODE == 5) { float t = Cf[idx] + v; Cf[idx] = t; Cdup[idx] = t; }
      }
    }
  }
}

// ---------------- fused OPM, software-pipelined: U(kh+1) overlaps proj(kh) ----------------
__global__ __launch_bounds__(256) void k_opm_fused(
    const bf16* __restrict__ a_t, const bf16* __restrict__ b_t,
    const bf16* __restrict__ Wt, const float* __restrict__ bias,
    const float* __restrict__ pair_in, float* __restrict__ pair_out) {
  __shared__ short U[32 * 512]; // 32 KB
  const int i = blockIdx.y;
  const int jg = blockIdx.x; // 0..7
  const int tid = threadIdx.x;
  const int w = tid >> 6, l = tid & 63;
  const int lr = l & 15, lk = l >> 4;
  const short* at = (const short*)a_t;
  const short* bt = (const short*)b_t;
  const short* wt = (const short*)Wt;

  short8 af[2][2];
  #pragma unroll
  for (int kh = 0; kh < 2; kh++)
    #pragma unroll
    for (int ks = 0; ks < 2; ks++)
      af[kh][ks] = *(const short8*)(at + ((size_t)i * 32 + kh * 16 + lr) * 64 + ks * 32 + lk * 8);

  floatx4 pacc[2][2] = {};

  auto computeU = [&](int kh, floatx4 (&ua)[2][8]) {
    #pragma unroll
    for (int sc = 0; sc < 2; sc++) {
      const size_t rowbase = ((size_t)(jg * 32 + sc * 16) << 5) + w * 128;
      #pragma unroll
      for (int ks = 0; ks < 2; ks++)
        #pragma unroll
        for (int nt = 0; nt < 8; nt++) {
          short8 bfr = *(const short8*)(bt + (rowbase + nt * 16 + lr) * 64 + ks * 32 + lk * 8);
          ua[sc][nt] = __builtin_amdgcn_mfma_f32_16x16x32_bf16(af[kh][ks], bfr, ua[sc][nt], 0, 0, 0);
        }
    }
  };
  auto writeU = [&](floatx4 (&ua)[2][8]) {
    #pragma unroll
    for (int sc = 0; sc < 2; sc++)
      #pragma unroll
      for (int nt = 0; nt < 8; nt++) {
        int npos = w * 128 + nt * 16 + lr;
        int jj = sc * 16 + (npos >> 5);
        int e = npos & 31;
        int g = e * 2 + (lk >> 1);
        int off = (lk & 1) * 4;
        short4s pk;
        pk.x = f2bfs(ua[sc][nt][0] * 0.015625f);
        pk.y = f2bfs(ua[sc][nt][1] * 0.015625f);
        pk.z = f2bfs(ua[sc][nt][2] * 0.015625f);
        pk.w = f2bfs(ua[sc][nt][3] * 0.015625f);
        *(short4s*)(&U[jj * 512 + ((g ^ (jj & 7)) << 3) + off]) = pk;
      }
  };
  auto proj = [&](int kh) {
    #pragma unroll 4
    for (int ks = 0; ks < 16; ks++) {
      short8 afp[2];
      #pragma unroll
      for (int mt = 0; mt < 2; mt++) {
        int row = mt * 16 + lr;
        int g = ks * 4 + lk;
        afp[mt] = *(const short8*)(&U[row * 512 + ((g ^ (row & 7)) << 3)]);
      }
      int wko = (ks * 2 + (lk >> 1)) * 32 + kh * 16 + (lk & 1) * 8;
      #pragma unroll
      for (int ntl = 0; ntl < 2; ntl++) {
        int d = (w * 2 + ntl) * 16 + lr;
        short8 bfr = *(const short8*)(wt + (size_t)d * 1024 + wko);
        #pragma unroll
        for (int mt = 0; mt < 2; mt++)
          pacc[mt][ntl] = __builtin_amdgcn_mfma_f32_16x16x32_bf16(afp[mt], bfr, pacc[mt][ntl], 0, 0, 0);
      }
    }
  };

  floatx4 ua[2][8] = {};
  computeU(0, ua);
  writeU(ua);
  __syncthreads();
  floatx4 ub[2][8] = {};
  computeU(1, ub);   // independent of LDS -> overlaps proj(0)'s loads/MFMAs
  proj(0);
  __syncthreads();
  writeU(ub);
  __syncthreads();
  proj(1);

  int jbase = jg * 32;
  #pragma unroll
  for (int ntl = 0; ntl < 2; ntl++) {
    int d = (w * 2 + ntl) * 16 + lr;
    float bv = bias[d];
    #pragma unroll
    for (int mt = 0; mt < 2; mt++)
      #pragma unroll
      for (int r = 0; r < 4; r++) {
        int j = jbase + mt * 16 + lk * 4 + r;
        size_t idx = ((size_t)i * L_ + j) * DP_ + d;
        pair_out[idx] = pair_in[idx] + pacc[mt][ntl][r] + bv;
      }
  }
}

// ---------------- MFMA attention: one (lead, head) per block; K/V staged once ----------------
template<int N>
__global__ __launch_bounds__(256) void k_attn_mfma(
    const bf16* __restrict__ qkv, bf16* __restrict__ out, int dmodel,
    int tokStride, int leadStride, int otokStride, int oleadStride, float scale) {
  constexpr int NT = N / 16;
  constexpr int NK = N / 32;
  constexpr int NIC = N / 64;
  __shared__ short Ks[N * 32];
  __shared__ short Vt[N * 32];
  __shared__ short Qs[2048];
  __shared__ short P[64 * N];

  const int lead = blockIdx.x;
  const int h = blockIdx.y;
  const short* base = (const short*)qkv + (size_t)lead * leadStride;
  const int qoff = h * 32, koff = dmodel + h * 32, voff = 2 * dmodel + h * 32;
  const int tid = threadIdx.x;
  const int l = tid & 63, w = tid >> 6;
  const int lr = l & 15, lk = l >> 4;

  for (int e = tid; e < N * 4; e += 256) {
    int j = e >> 2, kg = e & 3;
    short8 v = *(const short8*)(base + (size_t)j * tokStride + koff + kg * 8);
    *(short8*)(&Ks[(kg * N + j) * 8]) = v;
  }
  for (int e = tid; e < N * 32; e += 256) {
    int j = e >> 5, d = e & 31;
    Vt[((j >> 5) * 4 + ((j >> 3) & 3)) * 256 + d * 8 + (j & 7)] = base[(size_t)j * tokStride + voff + d];
  }
  __syncthreads();

  for (int ic = 0; ic < NIC; ic++) {
    {
      int r = tid >> 2, kg = tid & 3;
      short8 v = *(const short8*)(base + (size_t)(ic * 64 + r) * tokStride + qoff + kg * 8);
      *(short8*)(&Qs[(kg * 64 + r) * 8]) = v;
    }
    short8 aq = *(const short8*)(&Qs[(lk * 64 + w * 16 + lr) * 8]);
    floatx4 sa[NT];
    #pragma unroll
    for (int t = 0; t < NT; t++) {
      short8 bk = *(const short8*)(&Ks[(lk * N + t * 16 + lr) * 8]);
      floatx4 z = {0.f, 0.f, 0.f, 0.f};
      sa[t] = __builtin_amdgcn_mfma_f32_16x16x32_bf16(aq, bk, z, 0, 0, 0);
    }

    float mrow[4] = {-1e30f, -1e30f, -1e30f, -1e30f};
    #pragma unroll
    for (int t = 0; t < NT; t++)
      #pragma unroll
      for (int r = 0; r < 4; r++) {
        float s = fminf(fmaxf(sa[t][r] * scale, -50.f), 50.f);
        sa[t][r] = s;
        mrow[r] = fmaxf(mrow[r], s);
      }
    #pragma unroll
    for (int o = 1; o <= 8; o <<= 1)
      #pragma unroll
      for (int r = 0; r < 4; r++) mrow[r] = fmaxf(mrow[r], __shfl_xor(mrow[r], o));
    float srow[4] = {0.f, 0.f, 0.f, 0.f};
    #pragma unroll
    for (int t = 0; t < NT; t++)
      #pragma unroll
      for (int r = 0; r < 4; r++) {
        float p = __expf(sa[t][r] - mrow[r]);
        sa[t][r] = p;
        srow[r] += p;
      }
    #pragma unroll
    for (int o = 1; o <= 8; o <<= 1)
      #pragma unroll
      for (int r = 0; r < 4; r++) srow[r] += __shfl_xor(srow[r], o);
    float inv[4];
    #pragma unroll
    for (int r = 0; r < 4; r++) inv[r] = 1.f / srow[r];

    #pragma unroll
    for (int t = 0; t < NT; t++) {
      int c = t * 16 + lr;
      int kstep = c >> 5, kslot = (c >> 3) & 3, u = c & 7;
      #pragma unroll
      for (int r = 0; r < 4; r++) {
        int row = w * 16 + lk * 4 + r;
        P[((kstep * 4 + kslot) * 64 + row) * 8 + u] = f2bfs(sa[t][r] * inv[r]);
      }
    }

    floatx4 oacc[2] = {{0.f,0.f,0.f,0.f},{0.f,0.f,0.f,0.f}};
    #pragma unroll
    for (int ks = 0; ks < NK; ks++) {
      short8 ap = *(const short8*)(&P[((ks * 4 + lk) * 64 + w * 16 + lr) * 8]);
      #pragma unroll
      for (int ct = 0; ct < 2; ct++) {
        short8 bv = *(const short8*)(&Vt[((ks * 4 + lk) * 32 + ct * 16 + lr) * 8]);
        oacc[ct] = __builtin_amdgcn_mfma_f32_16x16x32_bf16(ap, bv, oacc[ct], 0, 0, 0);
      }
    }
    bf16* ob = out + (size_t)lead * oleadStride + h * 32;
    #pragma unroll
    for (int ct = 0; ct < 2; ct++)
      #pragma unroll
      for (int r = 0; r < 4; r++) {
        int tok = ic * 64 + w * 16 + lk * 4 + r;
        ob[(size_t)tok * otokStride + ct * 16 + lr] = __float2bfloat16(oacc[ct][r]);
      }
  }
}

extern "C" void kernel_launch(void* const* d_in, const int* in_sizes, int n_in,
                              void* d_out, int out_size, void* d_ws, size_t ws_size,
                              hipStream_t stream) {
  const float* msa_in    = (const float*)d_in[0];
  const float* pair_in   = (const float*)d_in[1];
  const float* row_ng    = (const float*)d_in[2];
  const float* row_nb    = (const float*)d_in[3];
  const float* row_qkv_w = (const float*)d_in[4];
  const float* row_qkv_b = (const float*)d_in[5];
  const float* row_out_w = (const float*)d_in[6];
  const float* row_out_b = (const float*)d_in[7];
  const float* col_ng    = (const float*)d_in[8];
  const float* col_nb    = (const float*)d_in[9];
  const float* col_qkv_w = (const float*)d_in[10];
  const float* col_qkv_b = (const float*)d_in[11];
  const float* col_out_w = (const float*)d_in[12];
  const float* col_out_b = (const float*)d_in[13];
  const float* ff_ng     = (const float*)d_in[14];
  const float* ff_nb     = (const float*)d_in[15];
  const float* ff_w1     = (const float*)d_in[16];
  const float* ff_b1     = (const float*)d_in[17];
  const float* ff_w2     = (const float*)d_in[18];
  const float* ff_b2     = (const float*)d_in[19];
  const float* op_ng     = (const float*)d_in[20];
  const float* op_nb     = (const float*)d_in[21];
  const float* op_a_w    = (const float*)d_in[22];
  const float* op_a_b    = (const float*)d_in[23];
  const float* op_b_w    = (const float*)d_in[24];
  const float* op_b_b    = (const float*)d_in[25];
  const float* op_out_w  = (const float*)d_in[26];
  const float* op_out_b  = (const float*)d_in[27];
  const float* tri_ng    = (const float*)d_in[28];
  const float* tri_nb    = (const float*)d_in[29];
  const float* tri_qkv_w = (const float*)d_in[30];
  const float* tri_qkv_b = (const float*)d_in[31];
  const float* tri_out_w = (const float*)d_in[32];
  const float* tri_out_b = (const float*)d_in[33];

  const int MT = S_ * L_;   // 16384
  const int PT = L_ * L_;   // 65536

  // ---- arena (byte offsets) ----
  char* ws = (char*)d_ws;
  float* msa_f  = (float*)(ws);                    // 16 MB
  float* pair_f = (float*)(ws + 16777216);         // 32 MB
  char*  X      = ws + 50331648;                   // 48 MB scratch (qkv bf16 / ffh bf16)
  bf16*  ln_b   = (bf16*)(ws + 100663296);         // 16 MB
  bf16*  ao_b   = (bf16*)(ws + 117440512);         // 16 MB
  bf16*  ab_buf = (bf16*)(ws + 134217728);         // 2 MB (MT x 64)
  bf16*  a_t    = (bf16*)(ws + 136314880);         // 1 MB
  bf16*  b_t    = (bf16*)(ws + 137363456);         // 1 MB
  bf16*  wts    = (bf16*)(ws + 138412032);         // ~2.6 MB
  float* bias_ab = (float*)(ws + 141557760);       // 64 floats

  bf16* row_qkv_wt = wts;                 // 768*256
  bf16* col_qkv_wt = row_qkv_wt + 196608;
  bf16* row_out_wt = col_qkv_wt + 196608; // 256*256
  bf16* col_out_wt = row_out_wt + 65536;
  bf16* ff_w1t     = col_out_wt + 65536;  // 1024*256
  bf16* ff_w2t     = ff_w1t + 262144;     // 256*1024
  bf16* op_ab_wt   = ff_w2t + 262144;     // 64*256
  bf16* op_out_wt  = op_ab_wt + 16384;    // 128*1024 (ec-permuted)
  bf16* tri_qkv_wt = op_out_wt + 131072;  // 384*128
  bf16* tri_out_wt = tri_qkv_wt + 49152;  // 128*128

  bf16* qkv_bf = (bf16*)X;
  bf16* ffh    = (bf16*)X;

  float* dout_msa  = (float*)d_out;
  float* dout_pair = (float*)d_out + (size_t)MT * DM_;

  const float scale = 0.17677669529663687f; // 1/sqrt(32)

  // ---- weight prep: 2 launches total ----
  WtJobs jobs;
  jobs.j[0] = {row_qkv_w, row_qkv_wt, 256, 768, 192};
  jobs.j[1] = {col_qkv_w, col_qkv_wt, 256, 768, 192};
  jobs.j[2] = {row_out_w, row_out_wt, 256, 256, 64};
  jobs.j[3] = {col_out_w, col_out_wt, 256, 256, 64};
  jobs.j[4] = {ff_w1, ff_w1t, 256, 1024, 256};
  jobs.j[5] = {ff_w2, ff_w2t, 1024, 256, 256};
  jobs.j[6] = {op_a_w, op_ab_wt, 256, 32, 8};
  jobs.j[7] = {op_b_w, op_ab_wt + 32 * 256, 256, 32, 8};
  jobs.j[8] = {tri_qkv_w, tri_qkv_wt, 128, 384, 48};
  jobs.j[9] = {tri_out_w, tri_out_wt, 128, 128, 16};
  k_wt_all<<<1104, 256, 0, stream>>>(jobs);
  k_wtopm<<<512, 256, 0, stream>>>(op_out_w, op_out_wt, op_a_b, op_b_b, bias_ab);

  // ---- 1. row attention (attend over L) ----
  k_ln<<<MT / 4, 256, 0, stream>>>(msa_in, ln_b, row_ng, row_nb, DM_);
  k_gemm<2><<<dim3(6, 128), 256, 0, stream>>>(ln_b, row_qkv_wt, row_qkv_b, nullptr, qkv_bf, nullptr, nullptr, MT, 768, 256, 1.f);
  k_attn_mfma<256><<<dim3(S_, H_), 256, 0, stream>>>(qkv_bf, ao_b, DM_, 768, L_ * 768, DM_, L_ * DM_, scale);
  k_gemm64<4><<<dim3(4, 256), 256, 0, stream>>>(ao_b, row_out_wt, row_out_b, msa_f, nullptr, msa_in, nullptr, MT, DM_, DM_, 1.f);

  // ---- 2. column attention (attend over S) ----
  k_ln<<<MT / 4, 256, 0, stream>>>(msa_f, ln_b, col_ng, col_nb, DM_);
  k_gemm<2><<<dim3(6, 128), 256, 0, stream>>>(ln_b, col_qkv_wt, col_qkv_b, nullptr, qkv_bf, nullptr, nullptr, MT, 768, 256, 1.f);
  k_attn_mfma<64><<<dim3(L_, H_), 256, 0, stream>>>(qkv_bf, ao_b, DM_, L_ * 768, 768, L_ * DM_, DM_, scale);
  k_gemm64<1><<<dim3(4, 256), 256, 0, stream>>>(ao_b, col_out_wt, col_out_b, msa_f, nullptr, nullptr, nullptr, MT, DM_, DM_, 1.f);

  // ---- 3. feed-forward (down-proj also writes d_out msa) ----
  k_ln<<<MT / 4, 256, 0, stream>>>(msa_f, ln_b, ff_ng, ff_nb, DM_);
  k_gemm<3><<<dim3(8, 128), 256, 0, stream>>>(ln_b, ff_w1t, ff_b1, nullptr, ffh, nullptr, nullptr, MT, 1024, 256, 1.f);
  k_gemm64<5><<<dim3(4, 256), 256, 0, stream>>>(ffh, ff_w2t, ff_b2, msa_f, nullptr, nullptr, dout_msa, MT, DM_, 1024, 1.f);

  // ---- 4. outer product mean -> pair ----
  k_ln<<<MT / 4, 256, 0, stream>>>(msa_f, ln_b, op_ng, op_nb, DM_);
  k_gemm64<2><<<dim3(1, 256), 256, 0, stream>>>(ln_b, op_ab_wt, bias_ab, nullptr, ab_buf, nullptr, nullptr, MT, 64, DM_, 1.f);
  k_topm<<<dim3(L_, 2), 256, 0, stream>>>(ab_buf, a_t, b_t);
  k_opm_fused<<<dim3(8, L_), 256, 0, stream>>>(a_t, b_t, op_out_wt, op_out_b, pair_in, pair_f);

  // ---- 5. triangle attention (out-proj writes d_out pair directly) ----
  k_ln<<<PT / 4, 256, 0, stream>>>(pair_f, ln_b, tri_ng, tri_nb, DP_);
  k_gemm<2><<<dim3(3, 512), 256, 0, stream>>>(ln_b, tri_qkv_wt, tri_qkv_b, nullptr, qkv_bf, nullptr, nullptr, PT, 384, DP_, 1.f);
  k_attn_mfma<256><<<dim3(L_, HT_), 256, 0, stream>>>(qkv_bf, ao_b, DP_, 384, L_ * 384, DP_, L_ * DP_, scale);
  k_gemm64<4><<<dim3(2, 1024), 256, 0, stream>>>(ao_b, tri_out_wt, tri_out_b, dout_pair, nullptr, pair_f, nullptr, PT, DP_, DP_, 1.f);
}

// Round 14
// 445.599 us; speedup vs baseline: 1.3372x; 1.0863x over previous
//
#include <hip/hip_runtime.h>
#include <hip/hip_bf16.h>

// MSA Transformer block: B=1, S=64, L=256, DM=256, DP=128, H=8, HT=4, NO=32
// Round 14: OPM reverted to r12 body (r13 pipeline spilled a resident block);
// gemm64 (more blocks) for qkv/ff1/tri-qkv — the lever that won in r13.

#define S_ 64
#define L_ 256
#define DM_ 256
#define DP_ 128
#define H_ 8
#define HT_ 4
#define NO_ 32

typedef __hip_bfloat16 bf16;
typedef short short4s __attribute__((ext_vector_type(4)));
typedef short short8 __attribute__((ext_vector_type(8)));
typedef float floatx4 __attribute__((ext_vector_type(4)));

__device__ __forceinline__ short f2bfs(float x) {
  union { float f; unsigned u; } v;
  v.f = x;
  unsigned r = (v.u + 0x7fffu + ((v.u >> 16) & 1u)) >> 16;
  return (short)r;
}

// ---------------- layernorm (4 rows per 256-thr block, 1 wave per row) ----------------
__global__ void k_ln(const float* __restrict__ src, bf16* __restrict__ dst,
                     const float* __restrict__ g, const float* __restrict__ bta, int D) {
  int row = blockIdx.x * 4 + (threadIdx.x >> 6);
  const float* x = src + (size_t)row * D;
  bf16* y = dst + (size_t)row * D;
  int t = threadIdx.x & 63;
  float v[4];
  int cnt = 0;
  float sum = 0.f;
  for (int e = t; e < D; e += 64) { float xv = x[e]; v[cnt++] = xv; sum += xv; }
  #pragma unroll
  for (int o = 32; o; o >>= 1) sum += __shfl_down(sum, o);
  sum = __shfl(sum, 0);
  float mean = sum / D;
  float var = 0.f;
  for (int k = 0; k < cnt; k++) { float d = v[k] - mean; var += d * d; }
  #pragma unroll
  for (int o = 32; o; o >>= 1) var += __shfl_down(var, o);
  var = __shfl(var, 0);
  float rstd = rsqrtf(var / D + 1e-5f);
  cnt = 0;
  for (int e = t; e < D; e += 64)
    y[e] = __float2bfloat16((v[cnt++] - mean) * rstd * g[e] + bta[e]);
}

// ---------------- fused weight transpose: 10 jobs, one launch ----------------
struct WtJob { const float* W; bf16* Wt; int K; int N; int nblk; };
struct WtJobs { WtJob j[10]; };

__global__ void k_wt_all(WtJobs jobs) {
  __shared__ float tile[32][33];
  int b = blockIdx.x;
  int ji = 0;
  while (ji < 9 && b >= jobs.j[ji].nblk) { b -= jobs.j[ji].nblk; ji++; }
  const float* W = jobs.j[ji].W;
  bf16* Wt = jobs.j[ji].Wt;
  int K = jobs.j[ji].K, N = jobs.j[ji].N;
  int kt = K >> 5;
  int k0 = (b % kt) * 32, n0 = (b / kt) * 32;
  int tid = threadIdx.x; // 256
  for (int e = tid; e < 1024; e += 256) {
    int r = e >> 5, c = e & 31;
    tile[r][c] = W[(size_t)(k0 + r) * N + (n0 + c)];
  }
  __syncthreads();
  for (int e = tid; e < 1024; e += 256) {
    int r = e >> 5, c = e & 31;
    Wt[(size_t)(n0 + r) * K + (k0 + c)] = __float2bfloat16(tile[c][r]);
  }
}

// ---------------- OPM proj weight permute + ab-bias concat ----------------
__global__ void k_wtopm(const float* __restrict__ W, bf16* __restrict__ Wt,
                        const float* __restrict__ ba, const float* __restrict__ bb,
                        float* __restrict__ bias_ab) {
  if (blockIdx.x == 0 && threadIdx.x < 64)
    bias_ab[threadIdx.x] = threadIdx.x < 32 ? ba[threadIdx.x] : bb[threadIdx.x - 32];
  int idx = blockIdx.x * 256 + threadIdx.x; // 131072
  int d = idx >> 10, kk = idx & 1023;
  int e = kk >> 5, c = kk & 31;
  Wt[idx] = __float2bfloat16(W[(size_t)(c * 32 + e) * 128 + d]);
}

// ---------------- OPM transpose ----------------
__global__ void k_topm(const bf16* __restrict__ ab, bf16* __restrict__ a_t,
                       bf16* __restrict__ b_t) {
  __shared__ bf16 tile[64][34];
  int i = blockIdx.x;       // L_
  int y = blockIdx.y;       // 0 = a, 1 = b
  bf16* out = y ? b_t : a_t;
  int tid = threadIdx.x; // 256
  for (int e = tid; e < 64 * 32; e += 256) {
    int s = e >> 5, c = e & 31;
    tile[s][c] = ab[((size_t)s * L_ + i) * 64 + y * 32 + c];
  }
  __syncthreads();
  for (int e = tid; e < 64 * 32; e += 256) {
    int c = e >> 6, s = e & 63;
    out[((size_t)i * NO_ + c) * S_ + s] = tile[s][c];
  }
}

// ---------------- bf16 MFMA GEMM, 64x64 tile ----------------
// MODE: 0 Cf=v | 1 Cf+=v | 2 Cb=bf16(v) | 3 Cb=bf16(relu v) | 4 Cf=Csrc+v
//       5 t=Cf+v; Cf=t; Cdup=t
template<int MODE>
__global__ void k_gemm64(const bf16* __restrict__ A, const bf16* __restrict__ Wt,
                         const float* __restrict__ bias, float* __restrict__ Cf,
                         bf16* __restrict__ Cb, const float* __restrict__ Csrc,
                         float* __restrict__ Cdup, int M, int N, int K, float scale) {
  __shared__ short As[64 * 64];
  __shared__ short Bs[64 * 64];
  const int tid = threadIdx.x;
  const int nwg = gridDim.x * gridDim.y;
  const int wgid = blockIdx.y * gridDim.x + blockIdx.x;
  const int q = nwg >> 3, r8 = nwg & 7;
  const int xcd = wgid & 7, loc = wgid >> 3;
  const int swz = (xcd < r8 ? xcd * (q + 1) : r8 * (q + 1) + (xcd - r8) * q) + loc;
  const int by = swz / gridDim.x, bx = swz - by * gridDim.x;
  const int m0 = by * 64, n0 = bx * 64;
  const int w = tid >> 6, l = tid & 63;
  const int wm = (w >> 1) * 32, wn = (w & 1) * 32;
  const int lr = l & 15, lk = l >> 4;
  floatx4 acc[2][2] = {};
  const short* Ash = (const short*)A;
  const short* Bsh = (const short*)Wt;
  for (int k0 = 0; k0 < K; k0 += 64) {
    for (int e = tid; e < 512; e += 256) {
      int r = e >> 3, kg = e & 7;
      short8 v = *(const short8*)(Ash + (size_t)(m0 + r) * K + k0 + kg * 8);
      *(short8*)(&As[r * 64 + ((kg ^ (r & 7)) * 8)]) = v;
    }
    for (int e = tid; e < 512; e += 256) {
      int r = e >> 3, kg = e & 7;
      int n = n0 + r;
      short8 v = {0, 0, 0, 0, 0, 0, 0, 0};
      if (n < N) v = *(const short8*)(Bsh + (size_t)n * K + k0 + kg * 8);
      *(short8*)(&Bs[r * 64 + ((kg ^ (r & 7)) * 8)]) = v;
    }
    __syncthreads();
    #pragma unroll
    for (int kk = 0; kk < 2; kk++) {
      short8 af[2], bfr[2];
      #pragma unroll
      for (int mi = 0; mi < 2; mi++) {
        int row = wm + mi * 16 + lr;
        int kg = kk * 4 + lk;
        af[mi] = *(const short8*)(&As[row * 64 + ((kg ^ (row & 7)) * 8)]);
      }
      #pragma unroll
      for (int ni = 0; ni < 2; ni++) {
        int row = wn + ni * 16 + lr;
        int kg = kk * 4 + lk;
        bfr[ni] = *(const short8*)(&Bs[row * 64 + ((kg ^ (row & 7)) * 8)]);
      }
      #pragma unroll
      for (int mi = 0; mi < 2; mi++)
        #pragma unroll
        for (int ni = 0; ni < 2; ni++)
          acc[mi][ni] = __builtin_amdgcn_mfma_f32_16x16x32_bf16(af[mi], bfr[ni], acc[mi][ni], 0, 0, 0);
    }
    __syncthreads();
  }
  #pragma unroll
  for (int ni = 0; ni < 2; ni++) {
    int n = n0 + wn + ni * 16 + lr;
    if (n >= N) continue;
    float bv = bias ? bias[n] : 0.f;
    #pragma unroll
    for (int mi = 0; mi < 2; mi++) {
      int mbase = m0 + wm + mi * 16 + lk * 4;
      #pragma unroll
      for (int r = 0; r < 4; r++) {
        float v = acc[mi][ni][r] * scale + bv;
        size_t idx = (size_t)(mbase + r) * N + n;
        if (MODE == 0) Cf[idx] = v;
        else if (MODE == 1) Cf[idx] += v;
        else if (MODE == 2) Cb[idx] = __float2bfloat16(v);
        else if (MODE == 3) Cb[idx] = __float2bfloat16(fmaxf(v, 0.f));
        else if (MODE == 4) Cf[idx] = Csrc[idx] + v;
        else if (MODE == 5) { float t = Cf[idx] + v; Cf[idx] = t; Cdup[idx] = t; }
      }
    }
  }
}

// ---------------- fused OPM (r12 body, known ~136 us) ----------------
__global__ __launch_bounds__(256) void k_opm_fused(
    const bf16* __restrict__ a_t, const bf16* __restrict__ b_t,
    const bf16* __restrict__ Wt, const float* __restrict__ bias,
    const float* __restrict__ pair_in, float* __restrict__ pair_out) {
  __shared__ short U[32 * 512]; // 32 KB
  const int i = blockIdx.y;
  const int jg = blockIdx.x; // 0..7
  const int tid = threadIdx.x;
  const int w = tid >> 6, l = tid & 63;
  const int lr = l & 15, lk = l >> 4;
  const short* at = (const short*)a_t;
  const short* bt = (const short*)b_t;
  const short* wt = (const short*)Wt;

  short8 af[2][2];
  #pragma unroll
  for (int kh = 0; kh < 2; kh++)
    #pragma unroll
    for (int ks = 0; ks < 2; ks++)
      af[kh][ks] = *(const short8*)(at + ((size_t)i * 32 + kh * 16 + lr) * 64 + ks * 32 + lk * 8);

  floatx4 pacc[2][2] = {};
  #pragma unroll
  for (int kh = 0; kh < 2; kh++) {
    #pragma unroll
    for (int sc = 0; sc < 2; sc++) {
      floatx4 uacc[8] = {};
      const size_t rowbase = ((size_t)(jg * 32 + sc * 16) << 5) + w * 128;
      #pragma unroll
      for (int ks = 0; ks < 2; ks++)
        #pragma unroll
        for (int nt = 0; nt < 8; nt++) {
          short8 bfr = *(const short8*)(bt + (rowbase + nt * 16 + lr) * 64 + ks * 32 + lk * 8);
          uacc[nt] = __builtin_amdgcn_mfma_f32_16x16x32_bf16(af[kh][ks], bfr, uacc[nt], 0, 0, 0);
        }
      #pragma unroll
      for (int nt = 0; nt < 8; nt++) {
        int npos = w * 128 + nt * 16 + lr;
        int jj = sc * 16 + (npos >> 5);
        int e = npos & 31;
        int g = e * 2 + (lk >> 1);
        int off = (lk & 1) * 4;
        short4s pk;
        pk.x = f2bfs(uacc[nt][0] * 0.015625f);
        pk.y = f2bfs(uacc[nt][1] * 0.015625f);
        pk.z = f2bfs(uacc[nt][2] * 0.015625f);
        pk.w = f2bfs(uacc[nt][3] * 0.015625f);
        *(short4s*)(&U[jj * 512 + ((g ^ (jj & 7)) << 3) + off]) = pk;
      }
    }
    __syncthreads();
    #pragma unroll 4
    for (int ks = 0; ks < 16; ks++) {
      short8 afp[2];
      #pragma unroll
      for (int mt = 0; mt < 2; mt++) {
        int row = mt * 16 + lr;
        int g = ks * 4 + lk;
        afp[mt] = *(const short8*)(&U[row * 512 + ((g ^ (row & 7)) << 3)]);
      }
      int wko = (ks * 2 + (lk >> 1)) * 32 + kh * 16 + (lk & 1) * 8;
      #pragma unroll
      for (int ntl = 0; ntl < 2; ntl++) {
        int d = (w * 2 + ntl) * 16 + lr;
        short8 bfr = *(const short8*)(wt + (size_t)d * 1024 + wko);
        #pragma unroll
        for (int mt = 0; mt < 2; mt++)
          pacc[mt][ntl] = __builtin_amdgcn_mfma_f32_16x16x32_bf16(afp[mt], bfr, pacc[mt][ntl], 0, 0, 0);
      }
    }
    __syncthreads();
  }
  int jbase = jg * 32;
  #pragma unroll
  for (int ntl = 0; ntl < 2; ntl++) {
    int d = (w * 2 + ntl) * 16 + lr;
    float bv = bias[d];
    #pragma unroll
    for (int mt = 0; mt < 2; mt++)
      #pragma unroll
      for (int r = 0; r < 4; r++) {
        int j = jbase + mt * 16 + lk * 4 + r;
        size_t idx = ((size_t)i * L_ + j) * DP_ + d;
        pair_out[idx] = pair_in[idx] + pacc[mt][ntl][r] + bv;
      }
  }
}

// ---------------- MFMA attention: one (lead, head) per block; K/V staged once ----------------
template<int N>
__global__ __launch_bounds__(256) void k_attn_mfma(
    const bf16* __restrict__ qkv, bf16* __restrict__ out, int dmodel,
    int tokStride, int leadStride, int otokStride, int oleadStride, float scale) {
  constexpr int NT = N / 16;
  constexpr int NK = N / 32;
  constexpr int NIC = N / 64;
  __shared__ short Ks[N * 32];
  __shared__ short Vt[N * 32];
  __shared__ short Qs[2048];
  __shared__ short P[64 * N];

  const int lead = blockIdx.x;
  const int h = blockIdx.y;
  const short* base = (const short*)qkv + (size_t)lead * leadStride;
  const int qoff = h * 32, koff = dmodel + h * 32, voff = 2 * dmodel + h * 32;
  const int tid = threadIdx.x;
  const int l = tid & 63, w = tid >> 6;
  const int lr = l & 15, lk = l >> 4;

  for (int e = tid; e < N * 4; e += 256) {
    int j = e >> 2, kg = e & 3;
    short8 v = *(const short8*)(base + (size_t)j * tokStride + koff + kg * 8);
    *(short8*)(&Ks[(kg * N + j) * 8]) = v;
  }
  for (int e = tid; e < N * 32; e += 256) {
    int j = e >> 5, d = e & 31;
    Vt[((j >> 5) * 4 + ((j >> 3) & 3)) * 256 + d * 8 + (j & 7)] = base[(size_t)j * tokStride + voff + d];
  }
  __syncthreads();

  for (int ic = 0; ic < NIC; ic++) {
    {
      int r = tid >> 2, kg = tid & 3;
      short8 v = *(const short8*)(base + (size_t)(ic * 64 + r) * tokStride + qoff + kg * 8);
      *(short8*)(&Qs[(kg * 64 + r) * 8]) = v;
    }
    short8 aq = *(const short8*)(&Qs[(lk * 64 + w * 16 + lr) * 8]);
    floatx4 sa[NT];
    #pragma unroll
    for (int t = 0; t < NT; t++) {
      short8 bk = *(const short8*)(&Ks[(lk * N + t * 16 + lr) * 8]);
      floatx4 z = {0.f, 0.f, 0.f, 0.f};
      sa[t] = __builtin_amdgcn_mfma_f32_16x16x32_bf16(aq, bk, z, 0, 0, 0);
    }

    float mrow[4] = {-1e30f, -1e30f, -1e30f, -1e30f};
    #pragma unroll
    for (int t = 0; t < NT; t++)
      #pragma unroll
      for (int r = 0; r < 4; r++) {
        float s = fminf(fmaxf(sa[t][r] * scale, -50.f), 50.f);
        sa[t][r] = s;
        mrow[r] = fmaxf(mrow[r], s);
      }
    #pragma unroll
    for (int o = 1; o <= 8; o <<= 1)
      #pragma unroll
      for (int r = 0; r < 4; r++) mrow[r] = fmaxf(mrow[r], __shfl_xor(mrow[r], o));
    float srow[4] = {0.f, 0.f, 0.f, 0.f};
    #pragma unroll
    for (int t = 0; t < NT; t++)
      #pragma unroll
      for (int r = 0; r < 4; r++) {
        float p = __expf(sa[t][r] - mrow[r]);
        sa[t][r] = p;
        srow[r] += p;
      }
    #pragma unroll
    for (int o = 1; o <= 8; o <<= 1)
      #pragma unroll
      for (int r = 0; r < 4; r++) srow[r] += __shfl_xor(srow[r], o);
    float inv[4];
    #pragma unroll
    for (int r = 0; r < 4; r++) inv[r] = 1.f / srow[r];

    #pragma unroll
    for (int t = 0; t < NT; t++) {
      int c = t * 16 + lr;
      int kstep = c >> 5, kslot = (c >> 3) & 3, u = c & 7;
      #pragma unroll
      for (int r = 0; r < 4; r++) {
        int row = w * 16 + lk * 4 + r;
        P[((kstep * 4 + kslot) * 64 + row) * 8 + u] = f2bfs(sa[t][r] * inv[r]);
      }
    }

    floatx4 oacc[2] = {{0.f,0.f,0.f,0.f},{0.f,0.f,0.f,0.f}};
    #pragma unroll
    for (int ks = 0; ks < NK; ks++) {
      short8 ap = *(const short8*)(&P[((ks * 4 + lk) * 64 + w * 16 + lr) * 8]);
      #pragma unroll
      for (int ct = 0; ct < 2; ct++) {
        short8 bv = *(const short8*)(&Vt[((ks * 4 + lk) * 32 + ct * 16 + lr) * 8]);
        oacc[ct] = __builtin_amdgcn_mfma_f32_16x16x32_bf16(ap, bv, oacc[ct], 0, 0, 0);
      }
    }
    bf16* ob = out + (size_t)lead * oleadStride + h * 32;
    #pragma unroll
    for (int ct = 0; ct < 2; ct++)
      #pragma unroll
      for (int r = 0; r < 4; r++) {
        int tok = ic * 64 + w * 16 + lk * 4 + r;
        ob[(size_t)tok * otokStride + ct * 16 + lr] = __float2bfloat16(oacc[ct][r]);
      }
  }
}

extern "C" void kernel_launch(void* const* d_in, const int* in_sizes, int n_in,
                              void* d_out, int out_size, void* d_ws, size_t ws_size,
                              hipStream_t stream) {
  const float* msa_in    = (const float*)d_in[0];
  const float* pair_in   = (const float*)d_in[1];
  const float* row_ng    = (const float*)d_in[2];
  const float* row_nb    = (const float*)d_in[3];
  const float* row_qkv_w = (const float*)d_in[4];
  const float* row_qkv_b = (const float*)d_in[5];
  const float* row_out_w = (const float*)d_in[6];
  const float* row_out_b = (const float*)d_in[7];
  const float* col_ng    = (const float*)d_in[8];
  const float* col_nb    = (const float*)d_in[9];
  const float* col_qkv_w = (const float*)d_in[10];
  const float* col_qkv_b = (const float*)d_in[11];
  const float* col_out_w = (const float*)d_in[12];
  const float* col_out_b = (const float*)d_in[13];
  const float* ff_ng     = (const float*)d_in[14];
  const float* ff_nb     = (const float*)d_in[15];
  const float* ff_w1     = (const float*)d_in[16];
  const float* ff_b1     = (const float*)d_in[17];
  const float* ff_w2     = (const float*)d_in[18];
  const float* ff_b2     = (const float*)d_in[19];
  const float* op_ng     = (const float*)d_in[20];
  const float* op_nb     = (const float*)d_in[21];
  const float* op_a_w    = (const float*)d_in[22];
  const float* op_a_b    = (const float*)d_in[23];
  const float* op_b_w    = (const float*)d_in[24];
  const float* op_b_b    = (const float*)d_in[25];
  const float* op_out_w  = (const float*)d_in[26];
  const float* op_out_b  = (const float*)d_in[27];
  const float* tri_ng    = (const float*)d_in[28];
  const float* tri_nb    = (const float*)d_in[29];
  const float* tri_qkv_w = (const float*)d_in[30];
  const float* tri_qkv_b = (const float*)d_in[31];
  const float* tri_out_w = (const float*)d_in[32];
  const float* tri_out_b = (const float*)d_in[33];

  const int MT = S_ * L_;   // 16384
  const int PT = L_ * L_;   // 65536

  // ---- arena (byte offsets) ----
  char* ws = (char*)d_ws;
  float* msa_f  = (float*)(ws);                    // 16 MB
  float* pair_f = (float*)(ws + 16777216);         // 32 MB
  char*  X      = ws + 50331648;                   // 48 MB scratch (qkv bf16 / ffh bf16)
  bf16*  ln_b   = (bf16*)(ws + 100663296);         // 16 MB
  bf16*  ao_b   = (bf16*)(ws + 117440512);         // 16 MB
  bf16*  ab_buf = (bf16*)(ws + 134217728);         // 2 MB (MT x 64)
  bf16*  a_t    = (bf16*)(ws + 136314880);         // 1 MB
  bf16*  b_t    = (bf16*)(ws + 137363456);         // 1 MB
  bf16*  wts    = (bf16*)(ws + 138412032);         // ~2.6 MB
  float* bias_ab = (float*)(ws + 141557760);       // 64 floats

  bf16* row_qkv_wt = wts;                 // 768*256
  bf16* col_qkv_wt = row_qkv_wt + 196608;
  bf16* row_out_wt = col_qkv_wt + 196608; // 256*256
  bf16* col_out_wt = row_out_wt + 65536;
  bf16* ff_w1t     = col_out_wt + 65536;  // 1024*256
  bf16* ff_w2t     = ff_w1t + 262144;     // 256*1024
  bf16* op_ab_wt   = ff_w2t + 262144;     // 64*256
  bf16* op_out_wt  = op_ab_wt + 16384;    // 128*1024 (ec-permuted)
  bf16* tri_qkv_wt = op_out_wt + 131072;  // 384*128
  bf16* tri_out_wt = tri_qkv_wt + 49152;  // 128*128

  bf16* qkv_bf = (bf16*)X;
  bf16* ffh    = (bf16*)X;

  float* dout_msa  = (float*)d_out;
  float* dout_pair = (float*)d_out + (size_t)MT * DM_;

  const float scale = 0.17677669529663687f; // 1/sqrt(32)

  // ---- weight prep: 2 launches total ----
  WtJobs jobs;
  jobs.j[0] = {row_qkv_w, row_qkv_wt, 256, 768, 192};
  jobs.j[1] = {col_qkv_w, col_qkv_wt, 256, 768, 192};
  jobs.j[2] = {row_out_w, row_out_wt, 256, 256, 64};
  jobs.j[3] = {col_out_w, col_out_wt, 256, 256, 64};
  jobs.j[4] = {ff_w1, ff_w1t, 256, 1024, 256};
  jobs.j[5] = {ff_w2, ff_w2t, 1024, 256, 256};
  jobs.j[6] = {op_a_w, op_ab_wt, 256, 32, 8};
  jobs.j[7] = {op_b_w, op_ab_wt + 32 * 256, 256, 32, 8};
  jobs.j[8] = {tri_qkv_w, tri_qkv_wt, 128, 384, 48};
  jobs.j[9] = {tri_out_w, tri_out_wt, 128, 128, 16};
  k_wt_all<<<1104, 256, 0, stream>>>(jobs);
  k_wtopm<<<512, 256, 0, stream>>>(op_out_w, op_out_wt, op_a_b, op_b_b, bias_ab);

  // ---- 1. row attention (attend over L) ----
  k_ln<<<MT / 4, 256, 0, stream>>>(msa_in, ln_b, row_ng, row_nb, DM_);
  k_gemm64<2><<<dim3(12, 256), 256, 0, stream>>>(ln_b, row_qkv_wt, row_qkv_b, nullptr, qkv_bf, nullptr, nullptr, MT, 768, 256, 1.f);
  k_attn_mfma<256><<<dim3(S_, H_), 256, 0, stream>>>(qkv_bf, ao_b, DM_, 768, L_ * 768, DM_, L_ * DM_, scale);
  k_gemm64<4><<<dim3(4, 256), 256, 0, stream>>>(ao_b, row_out_wt, row_out_b, msa_f, nullptr, msa_in, nullptr, MT, DM_, DM_, 1.f);

  // ---- 2. column attention (attend over S) ----
  k_ln<<<MT / 4, 256, 0, stream>>>(msa_f, ln_b, col_ng, col_nb, DM_);
  k_gemm64<2><<<dim3(12, 256), 256, 0, stream>>>(ln_b, col_qkv_wt, col_qkv_b, nullptr, qkv_bf, nullptr, nullptr, MT, 768, 256, 1.f);
  k_attn_mfma<64><<<dim3(L_, H_), 256, 0, stream>>>(qkv_bf, ao_b, DM_, L_ * 768, 768, L_ * DM_, DM_, scale);
  k_gemm64<1><<<dim3(4, 256), 256, 0, stream>>>(ao_b, col_out_wt, col_out_b, msa_f, nullptr, nullptr, nullptr, MT, DM_, DM_, 1.f);

  // ---- 3. feed-forward (down-proj also writes d_out msa) ----
  k_ln<<<MT / 4, 256, 0, stream>>>(msa_f, ln_b, ff_ng, ff_nb, DM_);
  k_gemm64<3><<<dim3(16, 256), 256, 0, stream>>>(ln_b, ff_w1t, ff_b1, nullptr, ffh, nullptr, nullptr, MT, 1024, 256, 1.f);
  k_gemm64<5><<<dim3(4, 256), 256, 0, stream>>>(ffh, ff_w2t, ff_b2, msa_f, nullptr, nullptr, dout_msa, MT, DM_, 1024, 1.f);

  // ---- 4. outer product mean -> pair ----
  k_ln<<<MT / 4, 256, 0, stream>>>(msa_f, ln_b, op_ng, op_nb, DM_);
  k_gemm64<2><<<dim3(1, 256), 256, 0, stream>>>(ln_b, op_ab_wt, bias_ab, nullptr, ab_buf, nullptr, nullptr, MT, 64, DM_, 1.f);
  k_topm<<<dim3(L_, 2), 256, 0, stream>>>(ab_buf, a_t, b_t);
  k_opm_fused<<<dim3(8, L_), 256, 0, stream>>>(a_t, b_t, op_out_wt, op_out_b, pair_in, pair_f);

  // ---- 5. triangle attention (out-proj writes d_out pair directly) ----
  k_ln<<<PT / 4, 256, 0, stream>>>(pair_f, ln_b, tri_ng, tri_nb, DP_);
  k_gemm64<2><<<dim3(6, 1024), 256, 0, stream>>>(ln_b, tri_qkv_wt, tri_qkv_b, nullptr, qkv_bf, nullptr, nullptr, PT, 384, DP_, 1.f);
  k_attn_mfma<256><<<dim3(L_, HT_), 256, 0, stream>>>(qkv_bf, ao_b, DP_, 384, L_ * 384, DP_, L_ * DP_, scale);
  k_gemm64<4><<<dim3(2, 1024), 256, 0, stream>>>(ao_b, tri_out_wt, tri_out_b, dout_pair, nullptr, pair_f, nullptr, PT, DP_, DP_, 1.f);
}